// Round 8
// baseline (301.405 us; speedup 1.0000x reference)
//
#include <hip/hip_runtime.h>
#include <math.h>

#define B_    2
#define TU_   1024
#define D_    80
#define H_    8
#define DH_   10
#define FFN_  2048
#define SEG_  32
#define RC_   8
#define LC_   50
#define NSEG_ 32
#define RCT_  256
#define L_    1280
#define NLAYERS_ 4
#define OUTD_ 768
#define EPS_  1e-5f
#define SCALE_ 0.31622776601683794f
#define NR_   (B_*L_)                 // 2560
#define KP_   96                      // K pad 80->96

typedef __attribute__((ext_vector_type(8))) short bf16x8;
typedef __attribute__((ext_vector_type(4))) float f32x4;
typedef unsigned short ushort_t;

__device__ inline ushort_t f2bf(float f) {
  union { float f; unsigned u; } x; x.f = f;
  unsigned r = x.u + 0x7fffu + ((x.u >> 16) & 1u);   // RNE
  return (ushort_t)(r >> 16);
}
__device__ inline float bf2f(ushort_t u) {
  union { unsigned u; float f; } x; x.u = ((unsigned)u) << 16; return x.f;
}

// ============ one-shot weight prep ============
#define S1_ (NLAYERS_*FFN_*KP_)        // w1T [l][n2048][k96]
#define S2_ (NLAYERS_*D_*FFN_)         // w2T [l][n80][k2048]
#define S3_ (NLAYERS_*256*KP_)         // wqkvT [l][n256][k96] (scale folded in q cols)
#define S4_ (NLAYERS_*D_*KP_)          // woT [l][n80][k96]
#define S5_ (OUTD_*KP_)                // pwT [n768][k96]
#define S6_ (NLAYERS_*240)             // bqkv fp32 [l][240]
#define WPREP_N_ (S1_+S2_+S3_+S4_+S5_+S6_)

__global__ void k_wprep(const float* __restrict__ w1, const float* __restrict__ w2,
    const float* __restrict__ wq, const float* __restrict__ wkv,
    const float* __restrict__ wo, const float* __restrict__ pw,
    const float* __restrict__ bq, const float* __restrict__ bkv,
    ushort_t* __restrict__ w1T, ushort_t* __restrict__ w2T,
    ushort_t* __restrict__ wqkvT, ushort_t* __restrict__ woT,
    ushort_t* __restrict__ pwT, float* __restrict__ bqkv) {
  int idx = blockIdx.x * blockDim.x + threadIdx.x;
  if (idx < S1_) {
    int k = idx % KP_, n = (idx / KP_) % FFN_, l = idx / (KP_*FFN_);
    w1T[idx] = (k < D_) ? f2bf(w1[(l*D_ + k)*FFN_ + n]) : 0;
    return;
  }
  idx -= S1_;
  if (idx < S2_) {
    int k = idx % FFN_, n = (idx / FFN_) % D_, l = idx / (FFN_*D_);
    w2T[idx] = f2bf(w2[(l*FFN_ + k)*D_ + n]);
    return;
  }
  idx -= S2_;
  if (idx < S3_) {
    int k = idx % KP_, n = (idx / KP_) % 256, l = idx / (KP_*256);
    float v = 0.f;
    if (k < D_ && n < 240) {
      if (n < D_) v = wq[(l*D_ + k)*D_ + n] * SCALE_;
      else        v = wkv[(l*D_ + k)*2*D_ + (n - D_)];
    }
    wqkvT[idx] = f2bf(v);
    return;
  }
  idx -= S3_;
  if (idx < S4_) {
    int k = idx % KP_, n = (idx / KP_) % D_, l = idx / (KP_*D_);
    woT[idx] = (k < D_) ? f2bf(wo[(l*D_ + k)*D_ + n]) : 0;
    return;
  }
  idx -= S4_;
  if (idx < S5_) {
    int k = idx % KP_, n = idx / KP_;
    pwT[idx] = (k < D_) ? f2bf(pw[k*OUTD_ + n]) : 0;
    return;
  }
  idx -= S5_;
  if (idx < S6_) {
    int c = idx % 240, l = idx / 240;
    bqkv[idx] = (c < D_) ? bq[l*D_ + c] * SCALE_ : bkv[l*2*D_ + (c - D_)];
  }
}

// ============ build x (gather) + layer-0 LN_in -> xnbf ============
__global__ __launch_bounds__(128) void k_build_ln(const float* __restrict__ mel,
    const float* __restrict__ lw, const float* __restrict__ lb,
    float* __restrict__ x, ushort_t* __restrict__ xnbf) {
  int row = blockIdx.x, tid = threadIdx.x;
  int b = row / L_, i = row % L_;
  int srow;
  if (i < RCT_) { int seg = i / RC_, j = i % RC_; srow = (seg+1)*SEG_ + j; }
  else          { srow = i - RCT_; }
  __shared__ float s1[128], s2[128];
  float v = (tid < D_) ? mel[(b*(TU_+RC_) + srow)*D_ + tid] : 0.f;
  if (tid < D_) x[row*D_ + tid] = v;
  s1[tid] = v; s2[tid] = v*v;
  __syncthreads();
  for (int off = 64; off > 0; off >>= 1) {
    if (tid < off) { s1[tid] += s1[tid+off]; s2[tid] += s2[tid+off]; }
    __syncthreads();
  }
  float mean = s1[0] * (1.f/D_);
  float var  = s2[0] * (1.f/D_) - mean*mean;
  float inv  = rsqrtf(var + EPS_);
  if (tid < D_)       xnbf[row*KP_ + tid] = f2bf((v - mean) * inv * lw[tid] + lb[tid]);
  else if (tid < KP_) xnbf[row*KP_ + tid] = 0;
}

// ============ QKV MFMA (layer 0 only) ============
__global__ __launch_bounds__(256) void k_qkv_mfma(const ushort_t* __restrict__ xnbf,
    const ushort_t* __restrict__ wqkvT, const float* __restrict__ bqkv,
    float* __restrict__ q, float* __restrict__ kv) {
  int wv = threadIdx.x >> 6, lane = threadIdx.x & 63;
  int bm = blockIdx.x * 64;
  int bn = blockIdx.y * 128 + wv*32;
  int r = lane & 15, g = lane >> 4;
  f32x4 acc[4][2] = {};
  const ushort_t* Ab = xnbf + (size_t)(bm + r)*KP_ + g*8;
  const ushort_t* Bb = wqkvT + (size_t)(bn + r)*KP_ + g*8;
  #pragma unroll
  for (int ks = 0; ks < KP_; ks += 32) {
    bf16x8 a[4], bfr[2];
    #pragma unroll
    for (int mf = 0; mf < 4; ++mf) a[mf]   = *(const bf16x8*)(Ab + mf*16*KP_ + ks);
    #pragma unroll
    for (int nf = 0; nf < 2; ++nf) bfr[nf] = *(const bf16x8*)(Bb + nf*16*KP_ + ks);
    #pragma unroll
    for (int mf = 0; mf < 4; ++mf)
      #pragma unroll
      for (int nf = 0; nf < 2; ++nf)
        acc[mf][nf] = __builtin_amdgcn_mfma_f32_16x16x32_bf16(a[mf], bfr[nf], acc[mf][nf], 0, 0, 0);
  }
  #pragma unroll
  for (int mf = 0; mf < 4; ++mf)
    #pragma unroll
    for (int nf = 0; nf < 2; ++nf) {
      int col = bn + nf*16 + r;
      if (col >= 240) continue;
      float bc = bqkv[col];
      #pragma unroll
      for (int rr = 0; rr < 4; ++rr) {
        int row = bm + mf*16 + g*4 + rr;
        float v = acc[mf][nf][rr] + bc;
        if (col < D_) q[row*D_ + col] = v;
        else          kv[row*2*D_ + (col - D_)] = v;
      }
    }
}

// ============ per-layer mega kernel: attn(own 16 rows) + WO + res + LN_ff +
//              FFN1 + FFN2 + reduce + res + LN_out -> x, LN_in(next), QKV(next) ============
// grid 160, 512 thr (8 waves). Each block owns 16 consecutive global rows.
#define POOLB_ 108544   // ff1sh(67584) + red(40960); attn phase reuses [0..85760)
__global__ __launch_bounds__(512) void k_layer(const float* __restrict__ qb,
    const float* __restrict__ kvb,
    const ushort_t* __restrict__ woT, const float* __restrict__ bo,
    const ushort_t* __restrict__ w1T, const float* __restrict__ b1,
    const ushort_t* __restrict__ w2T, const float* __restrict__ b2,
    const float* __restrict__ lfw, const float* __restrict__ lfb,
    const float* __restrict__ low, const float* __restrict__ lob,
    const float* __restrict__ liw, const float* __restrict__ lib, int mode,
    float* __restrict__ x, ushort_t* __restrict__ xnbf,
    const ushort_t* __restrict__ wqkvT_n, const float* __restrict__ bqkv_n,
    float* __restrict__ q, float* __restrict__ kv) {
  int tid = threadIdx.x;
  int wv = tid >> 6, lane = tid & 63;
  int r = lane & 15, g = lane >> 4;
  int bm = blockIdx.x * 16;          // global row base
  int b  = bm / L_;
  int i0 = bm % L_;

  __shared__ __align__(16) char pool[POOLB_];
  __shared__ ushort_t attsh[16][KP_];     // persistent: attn out (WO A-operand)
  __shared__ ushort_t hnsh[16][KP_];      // persistent: LN_ff out / LN_in(next) out
  __shared__ float    vres[16][D_];       // persistent: residual accumulator
  __shared__ float    inv_sh[4][16];

  // pool views — attn phase
  ushort_t (*ksh)[90][D_] = (ushort_t(*)[90][D_])(pool);            // [2][90][80] bf16
  ushort_t (*vsh)[90][D_] = (ushort_t(*)[90][D_])(pool + 28800);
  float    (*qsh)[D_]     = (float(*)[D_])(pool + 57600);           // [16][80]
  float    (*Ssh)[16][90] = (float(*)[16][90])(pool + 62720);       // [4][16][90]
  // pool views — ffn phase (after barriers; lifetimes disjoint)
  ushort_t (*ff1sh)[16][264] = (ushort_t(*)[16][264])(pool);        // [8][16][264]
  float    (*red)[16][D_]    = (float(*)[16][D_])(pool + 67584);    // [8][16][80]

  // ---- window setup ----
  int isR = (i0 < RCT_);
  int nw  = isR ? 2 : 1;
  int ws0 = isR ? (i0 >> 3) : ((i0 - RCT_) >> 5);
  int kcs[2], s0s[2];
  #pragma unroll
  for (int w = 0; w < 2; ++w) {
    int seg = ws0 + w;
    int s0 = seg*SEG_ - LC_; if (s0 < 0) s0 = 0;
    s0s[w] = s0;
    kcs[w] = RC_ + (seg+1)*SEG_ - s0;    // 40..90
  }

  // ---- stage K/V windows (bf16) + Q (fp32) + zero attsh pads ----
  for (int e = tid; e < nw*90*2*D_; e += 512) {
    int d = e % D_;
    int t2 = e / D_;
    int kvsel = t2 & 1;
    int t3 = t2 >> 1;
    int kk = t3 % 90;
    int w  = t3 / 90;
    if (kk < kcs[w]) {
      int seg = ws0 + w;
      int krow = (kk < RC_) ? seg*RC_ + kk : RCT_ + s0s[w] + (kk - RC_);
      float v = kvb[((size_t)b*L_ + krow)*2*D_ + kvsel*D_ + d];
      if (kvsel == 0) ksh[w][kk][d] = f2bf(v);
      else            vsh[w][kk][d] = f2bf(v);
    }
  }
  for (int e = tid; e < 16*D_; e += 512) {
    int ri = e / D_, d = e % D_;
    qsh[ri][d] = qb[(size_t)(bm + ri)*D_ + d];
  }
  if (tid < 256) attsh[tid >> 4][D_ + (tid & 15)] = 0;
  __syncthreads();

  // ---- attention: two head-groups of 4 ----
  for (int hg = 0; hg < 2; ++hg) {
    for (int e = tid; e < 16*4*90; e += 512) {
      int kk = e % 90;
      int t2 = e / 90;
      int qi = t2 & 15;
      int hh = t2 >> 4;
      int w = isR ? (qi >> 3) : 0;
      if (kk < kcs[w]) {
        int h = hg*4 + hh;
        float s = 0.f;
        #pragma unroll
        for (int d = 0; d < DH_; ++d)
          s += qsh[qi][h*DH_+d] * bf2f(ksh[w][kk][h*DH_+d]);
        Ssh[hh][qi][kk] = s;
      }
    }
    __syncthreads();
    {   // softmax: 64 rows x 8 lanes (exactly 512)
      int row = tid >> 3, j = tid & 7;
      int hh = row >> 4, qi = row & 15;
      int w = isR ? (qi >> 3) : 0;
      int kc = kcs[w];
      float pm = -INFINITY;
      for (int kk = j; kk < kc; kk += 8) pm = fmaxf(pm, Ssh[hh][qi][kk]);
      pm = fmaxf(pm, __shfl_xor(pm, 1, 8));
      pm = fmaxf(pm, __shfl_xor(pm, 2, 8));
      pm = fmaxf(pm, __shfl_xor(pm, 4, 8));
      float ps = 0.f;
      for (int kk = j; kk < kc; kk += 8) {
        float e2 = expf(Ssh[hh][qi][kk] - pm);
        Ssh[hh][qi][kk] = e2;
        ps += e2;
      }
      ps += __shfl_xor(ps, 1, 8);
      ps += __shfl_xor(ps, 2, 8);
      ps += __shfl_xor(ps, 4, 8);
      if (j == 0) inv_sh[hh][qi] = 1.f / ps;
    }
    __syncthreads();
    for (int e = tid; e < 16*DH_*4; e += 512) {   // PV: 640 outputs
      int d = e % DH_;
      int t2 = e / DH_;
      int qi = t2 & 15;
      int hh = t2 >> 4;
      int w = isR ? (qi >> 3) : 0;
      int h = hg*4 + hh;
      float acc = 0.f;
      int kc = kcs[w];
      for (int kk = 0; kk < kc; ++kk)
        acc += Ssh[hh][qi][kk] * bf2f(vsh[w][kk][h*DH_+d]);
      attsh[qi][h*DH_+d] = f2bf(acc * inv_sh[hh][qi]);
    }
    __syncthreads();
  }

  // ---- WO: waves 0..4 each compute one 16-col fragment (K=96) ----
  if (wv < 5) {
    f32x4 acc = {};
    #pragma unroll
    for (int ks = 0; ks < KP_; ks += 32) {
      bf16x8 a  = *(const bf16x8*)(&attsh[r][ks + g*8]);
      bf16x8 bb = *(const bf16x8*)(woT + (size_t)(wv*16 + r)*KP_ + ks + g*8);
      acc = __builtin_amdgcn_mfma_f32_16x16x32_bf16(a, bb, acc, 0, 0, 0);
    }
    #pragma unroll
    for (int rr = 0; rr < 4; ++rr)
      vres[g*4 + rr][wv*16 + r] = acc[rr];
  }
  __syncthreads();

  // ---- bias + residual + LN_ff -> hnsh (res kept in vres) ----
  if (tid < 256) {
    int row = tid >> 4, j = tid & 15;
    int grow = bm + row;
    float v[5], s = 0.f, ss = 0.f;
    #pragma unroll
    for (int c = 0; c < 5; ++c) {
      int col = j + c*16;
      v[c] = vres[row][col] + bo[col] + x[(size_t)grow*D_ + col];
      vres[row][col] = v[c];
      s += v[c]; ss += v[c]*v[c];
    }
    s  += __shfl_xor(s, 1, 16);  ss += __shfl_xor(ss, 1, 16);
    s  += __shfl_xor(s, 2, 16);  ss += __shfl_xor(ss, 2, 16);
    s  += __shfl_xor(s, 4, 16);  ss += __shfl_xor(ss, 4, 16);
    s  += __shfl_xor(s, 8, 16);  ss += __shfl_xor(ss, 8, 16);
    float mean = s * (1.f/D_);
    float var  = ss * (1.f/D_) - mean*mean;
    float inv  = rsqrtf(var + EPS_);
    #pragma unroll
    for (int c = 0; c < 5; ++c) {
      int col = j + c*16;
      hnsh[row][col] = f2bf((v[c] - mean) * inv * lfw[col] + lfb[col]);
    }
    hnsh[row][D_ + j] = 0;
  }
  __syncthreads();

  // ---- FFN1: M=16 x N=256(per wave) x K=96 ----
  f32x4 acc1[16];
  #pragma unroll
  for (int ni = 0; ni < 16; ++ni) acc1[ni] = (f32x4){0.f,0.f,0.f,0.f};
  int nbase = wv*256;
  #pragma unroll
  for (int ks = 0; ks < KP_; ks += 32) {
    bf16x8 a = *(const bf16x8*)(&hnsh[r][ks + g*8]);
    #pragma unroll
    for (int ni = 0; ni < 16; ++ni) {
      bf16x8 bb = *(const bf16x8*)(w1T + (size_t)(nbase + ni*16 + r)*KP_ + ks + g*8);
      acc1[ni] = __builtin_amdgcn_mfma_f32_16x16x32_bf16(a, bb, acc1[ni], 0, 0, 0);
    }
  }
  #pragma unroll
  for (int ni = 0; ni < 16; ++ni) {
    int col = nbase + ni*16 + r;
    float bc = b1[col];
    #pragma unroll
    for (int rr = 0; rr < 4; ++rr)
      ff1sh[wv][g*4 + rr][ni*16 + r] = f2bf(fmaxf(acc1[ni][rr] + bc, 0.f));
  }
  // same-wave write->read of ff1sh[wv]: compiler-ordered, no block barrier needed

  // ---- FFN2: M=16 x N=80 x K=256 (this wave's chunk) ----
  f32x4 acc2[5] = {};
  #pragma unroll
  for (int ks = 0; ks < 256; ks += 32) {
    bf16x8 a = *(const bf16x8*)(&ff1sh[wv][r][ks + g*8]);
    #pragma unroll
    for (int nf = 0; nf < 5; ++nf) {
      bf16x8 bb = *(const bf16x8*)(w2T + (size_t)(nf*16 + r)*FFN_ + wv*256 + ks + g*8);
      acc2[nf] = __builtin_amdgcn_mfma_f32_16x16x32_bf16(a, bb, acc2[nf], 0, 0, 0);
    }
  }
  #pragma unroll
  for (int nf = 0; nf < 5; ++nf)
    #pragma unroll
    for (int rr = 0; rr < 4; ++rr)
      red[wv][g*4 + rr][nf*16 + r] = acc2[nf][rr];
  __syncthreads();

  for (int e = tid; e < 16*D_; e += 512) {
    int row = e / D_, col = e % D_;
    float s = red[0][row][col];
    #pragma unroll
    for (int w = 1; w < 8; ++w) s += red[w][row][col];
    red[0][row][col] = s + b2[col] + vres[row][col];
  }
  __syncthreads();
  if (tid < 256) {
    int row = tid >> 4, j = tid & 15;
    float v[5], s = 0.f, ss = 0.f;
    #pragma unroll
    for (int c = 0; c < 5; ++c) {
      v[c] = red[0][row][j + c*16];
      s += v[c]; ss += v[c]*v[c];
    }
    s  += __shfl_xor(s, 1, 16);  ss += __shfl_xor(ss, 1, 16);
    s  += __shfl_xor(s, 2, 16);  ss += __shfl_xor(ss, 2, 16);
    s  += __shfl_xor(s, 4, 16);  ss += __shfl_xor(ss, 4, 16);
    s  += __shfl_xor(s, 8, 16);  ss += __shfl_xor(ss, 8, 16);
    float mean = s * (1.f/D_);
    float var  = ss * (1.f/D_) - mean*mean;
    float inv  = rsqrtf(var + EPS_);
    int grow = bm + row;
    float xs[5];
    float s2 = 0.f, ss2 = 0.f;
    #pragma unroll
    for (int c = 0; c < 5; ++c) {
      int col = j + c*16;
      xs[c] = (v[c] - mean) * inv * low[col] + lob[col];
      x[(size_t)grow*D_ + col] = xs[c];
      s2 += xs[c]; ss2 += xs[c]*xs[c];
    }
    if (mode == 0) {
      s2  += __shfl_xor(s2, 1, 16);  ss2 += __shfl_xor(ss2, 1, 16);
      s2  += __shfl_xor(s2, 2, 16);  ss2 += __shfl_xor(ss2, 2, 16);
      s2  += __shfl_xor(s2, 4, 16);  ss2 += __shfl_xor(ss2, 4, 16);
      s2  += __shfl_xor(s2, 8, 16);  ss2 += __shfl_xor(ss2, 8, 16);
      float m2 = s2 * (1.f/D_);
      float v2 = ss2 * (1.f/D_) - m2*m2;
      float i2 = rsqrtf(v2 + EPS_);
      #pragma unroll
      for (int c = 0; c < 5; ++c) {
        int col = j + c*16;
        ushort_t bv = f2bf((xs[c] - m2) * i2 * liw[col] + lib[col]);
        hnsh[row][col] = bv;               // stage for fused QKV
      }
      hnsh[row][D_ + j] = 0;
    } else {
      #pragma unroll
      for (int c = 0; c < 5; ++c)
        xnbf[(size_t)grow*KP_ + j + c*16] = f2bf(xs[c]);
      xnbf[(size_t)grow*KP_ + D_ + j] = 0;
    }
  }

  // ---- fused next-layer QKV: [16x96] @ [96x240] (15 N-tiles over 8 waves) ----
  if (mode == 0) {
    __syncthreads();
    for (int t = wv; t < 15; t += 8) {
      f32x4 acc = {};
      #pragma unroll
      for (int ks = 0; ks < KP_; ks += 32) {
        bf16x8 a  = *(const bf16x8*)(&hnsh[r][ks + g*8]);
        bf16x8 bb = *(const bf16x8*)(wqkvT_n + (size_t)(t*16 + r)*KP_ + ks + g*8);
        acc = __builtin_amdgcn_mfma_f32_16x16x32_bf16(a, bb, acc, 0, 0, 0);
      }
      int col = t*16 + r;
      float bc = bqkv_n[col];
      #pragma unroll
      for (int rr = 0; rr < 4; ++rr) {
        int row = bm + g*4 + rr;
        float v = acc[rr] + bc;
        if (col < D_) q[(size_t)row*D_ + col] = v;
        else          kv[(size_t)row*2*D_ + (col - D_)] = v;
      }
    }
  }
}

// ============ final proj MFMA (+ lengths tail) ============
__global__ __launch_bounds__(256) void k_proj_mfma(const ushort_t* __restrict__ xbf,
    const ushort_t* __restrict__ pwT, const float* __restrict__ pb,
    const int* __restrict__ len, float* __restrict__ out) {
  int wv = threadIdx.x >> 6, lane = threadIdx.x & 63;
  int bm = blockIdx.x * 64;
  int bn = blockIdx.y * 128 + wv*32;
  int b  = blockIdx.z;
  int r = lane & 15, g = lane >> 4;
  f32x4 acc[4][2] = {};
  const ushort_t* Ab = xbf + ((size_t)(b*L_ + RCT_ + bm) + r)*KP_ + g*8;
  const ushort_t* Bb = pwT + (size_t)(bn + r)*KP_ + g*8;
  #pragma unroll
  for (int ks = 0; ks < KP_; ks += 32) {
    bf16x8 a[4], bfr[2];
    #pragma unroll
    for (int mf = 0; mf < 4; ++mf) a[mf]   = *(const bf16x8*)(Ab + mf*16*KP_ + ks);
    #pragma unroll
    for (int nf = 0; nf < 2; ++nf) bfr[nf] = *(const bf16x8*)(Bb + nf*16*KP_ + ks);
    #pragma unroll
    for (int mf = 0; mf < 4; ++mf)
      #pragma unroll
      for (int nf = 0; nf < 2; ++nf)
        acc[mf][nf] = __builtin_amdgcn_mfma_f32_16x16x32_bf16(a[mf], bfr[nf], acc[mf][nf], 0, 0, 0);
  }
  #pragma unroll
  for (int mf = 0; mf < 4; ++mf)
    #pragma unroll
    for (int nf = 0; nf < 2; ++nf) {
      int col = bn + nf*16 + r;
      float bc = pb[col];
      #pragma unroll
      for (int rr = 0; rr < 4; ++rr) {
        int row = bm + mf*16 + g*4 + rr;
        out[((size_t)b*TU_ + row)*OUTD_ + col] = acc[mf][nf][rr] + bc;
      }
    }
  if (blockIdx.x == 0 && blockIdx.y == 0 && blockIdx.z == 0 && threadIdx.x < B_)
    out[(size_t)B_*TU_*OUTD_ + threadIdx.x] = (float)len[threadIdx.x];
}

extern "C" void kernel_launch(void* const* d_in, const int* in_sizes, int n_in,
                              void* d_out, int out_size, void* d_ws, size_t ws_size,
                              hipStream_t stream) {
  const float* mel     = (const float*)d_in[0];
  const int*   lengths = (const int*)  d_in[1];
  const float* ln_in_w = (const float*)d_in[2];
  const float* ln_in_b = (const float*)d_in[3];
  const float* wq      = (const float*)d_in[4];
  const float* bq      = (const float*)d_in[5];
  const float* wkv     = (const float*)d_in[6];
  const float* bkv     = (const float*)d_in[7];
  const float* wo      = (const float*)d_in[8];
  const float* bo      = (const float*)d_in[9];
  const float* ln_ff_w = (const float*)d_in[10];
  const float* ln_ff_b = (const float*)d_in[11];
  const float* w1      = (const float*)d_in[12];
  const float* b1      = (const float*)d_in[13];
  const float* w2      = (const float*)d_in[14];
  const float* b2      = (const float*)d_in[15];
  const float* ln_o_w  = (const float*)d_in[16];
  const float* ln_o_b  = (const float*)d_in[17];
  const float* pw      = (const float*)d_in[18];
  const float* pb      = (const float*)d_in[19];
  float* out = (float*)d_out;

  float* ws = (float*)d_ws;
  float* x     = ws; ws += NR_*D_;
  float* qb    = ws; ws += NR_*D_;
  float* kvb   = ws; ws += NR_*2*D_;
  float* bqkv  = ws; ws += NLAYERS_*240;
  ushort_t* us = (ushort_t*)ws;
  ushort_t* xnbf  = us; us += NR_*KP_;
  ushort_t* w1T   = us; us += S1_;
  ushort_t* w2T   = us; us += S2_;
  ushort_t* wqkvT = us; us += S3_;
  ushort_t* woT   = us; us += S4_;
  ushort_t* pwT   = us; us += S5_;

  k_wprep<<<(WPREP_N_ + 255)/256, 256, 0, stream>>>(w1, w2, wq, wkv, wo, pw, bq, bkv,
                                                    w1T, w2T, wqkvT, woT, pwT, bqkv);
  k_build_ln<<<NR_, 128, 0, stream>>>(mel, ln_in_w, ln_in_b, x, xnbf);
  k_qkv_mfma<<<dim3(NR_/64, 2), 256, 0, stream>>>(xnbf, wqkvT, bqkv, qb, kvb);

  for (int l = 0; l < NLAYERS_; ++l) {
    int last = (l == NLAYERS_-1);
    k_layer<<<NR_/16, 512, 0, stream>>>(qb, kvb,
        woT + l*D_*KP_, bo + l*D_,
        w1T + l*FFN_*KP_, b1 + l*FFN_,
        w2T + l*D_*FFN_, b2 + l*D_,
        ln_ff_w + l*D_, ln_ff_b + l*D_,
        ln_o_w + l*D_, ln_o_b + l*D_,
        ln_in_w + (last ? 0 : (l+1)*D_), ln_in_b + (last ? 0 : (l+1)*D_),
        last, x, xnbf,
        wqkvT + (last ? 0 : (l+1)*256*KP_), bqkv + (last ? 0 : (l+1)*240),
        qb, kvb);
  }

  k_proj_mfma<<<dim3(TU_/64, OUTD_/128, B_), 256, 0, stream>>>(xnbf, pwT, pb, lengths, out);
}

// Round 9
// 196.707 us; speedup vs baseline: 1.5323x; 1.5323x over previous
//
#include <hip/hip_runtime.h>
#include <math.h>

#define B_    2
#define TU_   1024
#define D_    80
#define H_    8
#define DH_   10
#define FFN_  2048
#define SEG_  32
#define RC_   8
#define LC_   50
#define NSEG_ 32
#define RCT_  256
#define L_    1280
#define NLAYERS_ 4
#define OUTD_ 768
#define EPS_  1e-5f
#define SCALE_ 0.31622776601683794f
#define NR_   (B_*L_)                 // 2560
#define KP_   96                      // K pad 80->96

typedef __attribute__((ext_vector_type(8))) short bf16x8;
typedef __attribute__((ext_vector_type(4))) float f32x4;
typedef unsigned short ushort_t;
typedef unsigned char uchar_t;
typedef long i64_t;

__device__ inline ushort_t f2bf(float f) {
  union { float f; unsigned u; } x; x.f = f;
  unsigned r = x.u + 0x7fffu + ((x.u >> 16) & 1u);   // RNE
  return (ushort_t)(r >> 16);
}

// float -> fp8 e4m3fn (OCP), RNE, saturating. Inputs pre-scaled to avoid subnormals.
__device__ inline uchar_t f2fp8(float f) {
  union { float f; unsigned u; } x; x.f = f;
  unsigned sgn = (x.u >> 31) << 7;
  float a = fabsf(f);
  if (a >= 448.f) return (uchar_t)(sgn | 0x7E);
  if (a < 0.015625f) {                       // subnormal: ulp 2^-9
    int m = (int)(a * 512.f + 0.5f);
    if (m >= 8) return (uchar_t)(sgn | 0x08);
    return (uchar_t)(sgn | m);
  }
  unsigned u = x.u;
  u += 0xFFFFFu + ((u >> 20) & 1u);          // RNE at mantissa bit 20
  int e = (int)((u >> 23) & 0xFF) - 120;     // -127 + 7
  unsigned m = (u >> 20) & 7u;
  if (e >= 16 || (e == 15 && m == 7)) return (uchar_t)(sgn | 0x7E);
  return (uchar_t)(sgn | (e << 3) | m);
}

// ============ one-shot weight prep ============
#define S1_ (NLAYERS_*FFN_*KP_)        // w18 fp8 [l][n2048][k96], x16
#define S2_ (NLAYERS_*D_*FFN_)         // w28 fp8 [l][n80][k2048], x16
#define S3_ (NLAYERS_*256*KP_)         // wqkvT bf16 [l][n256][k96] (scale folded in q cols)
#define S4_ (NLAYERS_*D_*KP_)          // woT bf16 [l][n80][k96]
#define S5_ (OUTD_*KP_)                // pwT bf16 [n768][k96]
#define S6_ (NLAYERS_*240)             // bqkv fp32 [l][240]
#define WPREP_N_ (S1_+S2_+S3_+S4_+S5_+S6_)

__global__ void k_wprep(const float* __restrict__ w1, const float* __restrict__ w2,
    const float* __restrict__ wq, const float* __restrict__ wkv,
    const float* __restrict__ wo, const float* __restrict__ pw,
    const float* __restrict__ bq, const float* __restrict__ bkv,
    uchar_t* __restrict__ w18, uchar_t* __restrict__ w28,
    ushort_t* __restrict__ wqkvT, ushort_t* __restrict__ woT,
    ushort_t* __restrict__ pwT, float* __restrict__ bqkv) {
  int idx = blockIdx.x * blockDim.x + threadIdx.x;
  if (idx < S1_) {
    int k = idx % KP_, n = (idx / KP_) % FFN_, l = idx / (KP_*FFN_);
    w18[idx] = (k < D_) ? f2fp8(w1[(l*D_ + k)*FFN_ + n] * 16.f) : 0;
    return;
  }
  idx -= S1_;
  if (idx < S2_) {
    int k = idx % FFN_, n = (idx / FFN_) % D_, l = idx / (FFN_*D_);
    w28[idx] = f2fp8(w2[(l*FFN_ + k)*D_ + n] * 16.f);
    return;
  }
  idx -= S2_;
  if (idx < S3_) {
    int k = idx % KP_, n = (idx / KP_) % 256, l = idx / (KP_*256);
    float v = 0.f;
    if (k < D_ && n < 240) {
      if (n < D_) v = wq[(l*D_ + k)*D_ + n] * SCALE_;
      else        v = wkv[(l*D_ + k)*2*D_ + (n - D_)];
    }
    wqkvT[idx] = f2bf(v);
    return;
  }
  idx -= S3_;
  if (idx < S4_) {
    int k = idx % KP_, n = (idx / KP_) % D_, l = idx / (KP_*D_);
    woT[idx] = (k < D_) ? f2bf(wo[(l*D_ + k)*D_ + n]) : 0;
    return;
  }
  idx -= S4_;
  if (idx < S5_) {
    int k = idx % KP_, n = idx / KP_;
    pwT[idx] = (k < D_) ? f2bf(pw[k*OUTD_ + n]) : 0;
    return;
  }
  idx -= S5_;
  if (idx < S6_) {
    int c = idx % 240, l = idx / 240;
    bqkv[idx] = (c < D_) ? bq[l*D_ + c] * SCALE_ : bkv[l*2*D_ + (c - D_)];
  }
}

// ============ merged: gather mel -> x + layer-0 LN_in + QKV MFMA -> q/kv ============
// grid 160, 512 thr (8 waves), 16 rows/block.
__global__ __launch_bounds__(512) void k_build_qkv(const float* __restrict__ mel,
    const float* __restrict__ lw, const float* __restrict__ lb,
    const ushort_t* __restrict__ wqkvT, const float* __restrict__ bqkv,
    float* __restrict__ x, float* __restrict__ q, float* __restrict__ kv) {
  int tid = threadIdx.x;
  int wv = tid >> 6, lane = tid & 63;
  int r = lane & 15, g = lane >> 4;
  int bm = blockIdx.x * 16;
  __shared__ ushort_t hnsh[16][KP_];

  if (tid < 256) {
    int row = tid >> 4, j = tid & 15;
    int grow = bm + row;
    int b = grow / L_, i = grow % L_;
    int srow = (i < RCT_) ? ((i >> 3) + 1)*SEG_ + (i & 7) : i - RCT_;
    float v[5], s = 0.f, ss = 0.f;
    #pragma unroll
    for (int c = 0; c < 5; ++c) {
      int col = j + c*16;
      v[c] = mel[((size_t)b*(TU_+RC_) + srow)*D_ + col];
      x[(size_t)grow*D_ + col] = v[c];
      s += v[c]; ss += v[c]*v[c];
    }
    s  += __shfl_xor(s, 1, 16);  ss += __shfl_xor(ss, 1, 16);
    s  += __shfl_xor(s, 2, 16);  ss += __shfl_xor(ss, 2, 16);
    s  += __shfl_xor(s, 4, 16);  ss += __shfl_xor(ss, 4, 16);
    s  += __shfl_xor(s, 8, 16);  ss += __shfl_xor(ss, 8, 16);
    float mean = s * (1.f/D_);
    float var  = ss * (1.f/D_) - mean*mean;
    float inv  = rsqrtf(var + EPS_);
    #pragma unroll
    for (int c = 0; c < 5; ++c) {
      int col = j + c*16;
      hnsh[row][col] = f2bf((v[c] - mean) * inv * lw[col] + lb[col]);
    }
    hnsh[row][D_ + j] = 0;
  }
  __syncthreads();

  for (int t = wv; t < 15; t += 8) {
    f32x4 acc = {};
    #pragma unroll
    for (int ks = 0; ks < KP_; ks += 32) {
      bf16x8 a  = *(const bf16x8*)(&hnsh[r][ks + g*8]);
      bf16x8 bb = *(const bf16x8*)(wqkvT + (size_t)(t*16 + r)*KP_ + ks + g*8);
      acc = __builtin_amdgcn_mfma_f32_16x16x32_bf16(a, bb, acc, 0, 0, 0);
    }
    int col = t*16 + r;
    float bc = bqkv[col];
    #pragma unroll
    for (int rr = 0; rr < 4; ++rr) {
      int row = bm + g*4 + rr;
      float v = acc[rr] + bc;
      if (col < D_) q[(size_t)row*D_ + col] = v;
      else          kv[(size_t)row*2*D_ + (col - D_)] = v;
    }
  }
}

// ============ block-sparse attention -> attbf bf16 [2560][96] ============
__global__ __launch_bounds__(256) void k_attn(const float* __restrict__ q,
    const float* __restrict__ kv, ushort_t* __restrict__ att) {
  int seg = blockIdx.x, b = blockIdx.y, h = blockIdx.z;
  int tid = threadIdx.x;
  int seg_start = seg*SEG_ - LC_; if (seg_start < 0) seg_start = 0;
  int kc = RC_ + (seg+1)*SEG_ - seg_start;       // <= 90
  __shared__ float Ksh[90][DH_];
  __shared__ float Vsh[90][DH_];
  __shared__ float Qsh[40][DH_];
  __shared__ float Ssh[40][90];
  __shared__ float inv_sh[40];
  for (int idx = tid; idx < kc*DH_; idx += 256) {
    int kk = idx / DH_, d = idx % DH_;
    int krow = (kk < RC_) ? seg*RC_ + kk : RCT_ + seg_start + (kk - RC_);
    const float* base = kv + (b*L_ + krow)*2*D_ + h*DH_ + d;
    Ksh[kk][d] = base[0];
    Vsh[kk][d] = base[D_];
  }
  for (int idx = tid; idx < 40*DH_; idx += 256) {
    int qi = idx / DH_, d = idx % DH_;
    int qrow = (qi < RC_) ? seg*RC_ + qi : RCT_ + seg*SEG_ + (qi - RC_);
    Qsh[qi][d] = q[(b*L_ + qrow)*D_ + h*DH_ + d];
  }
  __syncthreads();
  for (int p = tid; p < 40*kc; p += 256) {
    int qi = p / kc, kk = p - qi*kc;
    float s = 0.f;
    #pragma unroll
    for (int d = 0; d < DH_; ++d) s += Qsh[qi][d] * Ksh[kk][d];
    Ssh[qi][kk] = s;
  }
  __syncthreads();
  if (tid < 160) {
    int row = tid >> 2, j = tid & 3;
    float pm = -INFINITY;
    for (int kk = j; kk < kc; kk += 4) pm = fmaxf(pm, Ssh[row][kk]);
    pm = fmaxf(pm, __shfl_xor(pm, 1, 4));
    pm = fmaxf(pm, __shfl_xor(pm, 2, 4));
    float ps = 0.f;
    for (int kk = j; kk < kc; kk += 4) {
      float e = expf(Ssh[row][kk] - pm);
      Ssh[row][kk] = e;
      ps += e;
    }
    ps += __shfl_xor(ps, 1, 4);
    ps += __shfl_xor(ps, 2, 4);
    if (j == 0) inv_sh[row] = 1.f / ps;
  }
  __syncthreads();
  for (int o = tid; o < 40*DH_; o += 256) {
    int qi = o / DH_, d = o - qi*DH_;
    float acc = 0.f;
    for (int kk = 0; kk < kc; ++kk) acc += Ssh[qi][kk] * Vsh[kk][d];
    int qrow = (qi < RC_) ? seg*RC_ + qi : RCT_ + seg*SEG_ + (qi - RC_);
    att[(b*L_ + qrow)*KP_ + h*DH_ + d] = f2bf(acc * inv_sh[qi]);
  }
  if (h == 0) {  // zero K-pad cols 80..95
    for (int idx = tid; idx < 40*16; idx += 256) {
      int qi = idx >> 4, c = D_ + (idx & 15);
      int qrow = (qi < RC_) ? seg*RC_ + qi : RCT_ + seg*SEG_ + (qi - RC_);
      att[(b*L_ + qrow)*KP_ + c] = 0;
    }
  }
}

// ============ fused per-layer tail: WO + res + LN_ff + FFN1(fp8) + FFN2(fp8) +
//              reduce + res + LN_out -> x, LN_in(next) -> QKV(next) ============
// grid 160, 512 thr. 16 rows/block; wave wv owns ff1 cols [wv*256, (wv+1)*256).
__global__ __launch_bounds__(512) void k_ffn_fused(const ushort_t* __restrict__ attbf,
    const ushort_t* __restrict__ woT, const float* __restrict__ bo,
    const uchar_t* __restrict__ w18, const float* __restrict__ b1,
    const uchar_t* __restrict__ w28, const float* __restrict__ b2,
    const float* __restrict__ lfw, const float* __restrict__ lfb,
    const float* __restrict__ low, const float* __restrict__ lob,
    const float* __restrict__ liw, const float* __restrict__ lib, int mode,
    float* __restrict__ x, ushort_t* __restrict__ xnbf,
    const ushort_t* __restrict__ wqkvT_n, const float* __restrict__ bqkv_n,
    float* __restrict__ q, float* __restrict__ kv) {
  int tid = threadIdx.x;
  int wv = tid >> 6, lane = tid & 63;
  int r = lane & 15, g = lane >> 4;
  int bm = blockIdx.x * 16;
  __shared__ ushort_t attsh[16][KP_];
  __shared__ ushort_t hnsh[16][KP_];
  __shared__ uchar_t  hn8[16][104];          // fp8 LN_ff out (FFN1 A)
  __shared__ uchar_t  ff18[8][16][272];      // fp8 relu(ff1)*8
  __shared__ float    red[8][16][D_];
  __shared__ float    vsh[16][D_];           // WO out, then residual

  if (tid < 192) {
    int row = tid / 12, c = (tid % 12) * 8;
    *(bf16x8*)&attsh[row][c] = *(const bf16x8*)(attbf + (size_t)(bm+row)*KP_ + c);
  }
  __syncthreads();

  // ---- WO: waves 0..4 each compute one 16-col fragment (K=96, bf16) ----
  if (wv < 5) {
    f32x4 acc = {};
    #pragma unroll
    for (int ks = 0; ks < KP_; ks += 32) {
      bf16x8 a  = *(const bf16x8*)(&attsh[r][ks + g*8]);
      bf16x8 bb = *(const bf16x8*)(woT + (size_t)(wv*16 + r)*KP_ + ks + g*8);
      acc = __builtin_amdgcn_mfma_f32_16x16x32_bf16(a, bb, acc, 0, 0, 0);
    }
    #pragma unroll
    for (int rr = 0; rr < 4; ++rr)
      vsh[g*4 + rr][wv*16 + r] = acc[rr];
  }
  __syncthreads();

  // ---- bias + residual + LN_ff -> hnsh(bf16 unused later) / hn8(fp8) ----
  if (tid < 256) {
    int row = tid >> 4, j = tid & 15;
    int grow = bm + row;
    float v[5], s = 0.f, ss = 0.f;
    #pragma unroll
    for (int c = 0; c < 5; ++c) {
      int col = j + c*16;
      v[c] = vsh[row][col] + bo[col] + x[(size_t)grow*D_ + col];
      vsh[row][col] = v[c];
      s += v[c]; ss += v[c]*v[c];
    }
    s  += __shfl_xor(s, 1, 16);  ss += __shfl_xor(ss, 1, 16);
    s  += __shfl_xor(s, 2, 16);  ss += __shfl_xor(ss, 2, 16);
    s  += __shfl_xor(s, 4, 16);  ss += __shfl_xor(ss, 4, 16);
    s  += __shfl_xor(s, 8, 16);  ss += __shfl_xor(ss, 8, 16);
    float mean = s * (1.f/D_);
    float var  = ss * (1.f/D_) - mean*mean;
    float inv  = rsqrtf(var + EPS_);
    #pragma unroll
    for (int c = 0; c < 5; ++c) {
      int col = j + c*16;
      hn8[row][col] = f2fp8((v[c] - mean) * inv * lfw[col] + lfb[col]);
    }
    hn8[row][D_ + j] = 0;   // zero pad cols 80..95 (avoid NaN garbage)
  }
  __syncthreads();

  // ---- FFN1 fp8: M=16 x N=256(per wave) x K=96; out = acc/16 + b1, relu, x8 -> fp8 ----
  f32x4 acc1[16];
  #pragma unroll
  for (int ni = 0; ni < 16; ++ni) acc1[ni] = (f32x4){0.f,0.f,0.f,0.f};
  int nbase = wv*256;
  #pragma unroll
  for (int ks = 0; ks < KP_; ks += 32) {
    i64_t a = *(const i64_t*)(&hn8[r][ks + g*8]);
    #pragma unroll
    for (int ni = 0; ni < 16; ++ni) {
      i64_t bb = *(const i64_t*)(w18 + (size_t)(nbase + ni*16 + r)*KP_ + ks + g*8);
      acc1[ni] = __builtin_amdgcn_mfma_f32_16x16x32_fp8_fp8(a, bb, acc1[ni], 0, 0, 0);
    }
  }
  #pragma unroll
  for (int ni = 0; ni < 16; ++ni) {
    int col = nbase + ni*16 + r;
    float bc = b1[col];
    #pragma unroll
    for (int rr = 0; rr < 4; ++rr) {
      float v = acc1[ni][rr] * 0.0625f + bc;               // /16 (weight scale)
      ff18[wv][g*4 + rr][ni*16 + r] = f2fp8(fmaxf(v, 0.f) * 8.f);
    }
  }
  // same-wave write->read of ff18[wv]: compiler-ordered, no block barrier needed

  // ---- FFN2 fp8: M=16 x N=80 x K=256 (this wave's chunk) ----
  f32x4 acc2[5] = {};
  #pragma unroll
  for (int ks = 0; ks < 256; ks += 32) {
    i64_t a = *(const i64_t*)(&ff18[wv][r][ks + g*8]);
    #pragma unroll
    for (int nf = 0; nf < 5; ++nf) {
      i64_t bb = *(const i64_t*)(w28 + (size_t)(nf*16 + r)*FFN_ + wv*256 + ks + g*8);
      acc2[nf] = __builtin_amdgcn_mfma_f32_16x16x32_fp8_fp8(a, bb, acc2[nf], 0, 0, 0);
    }
  }
  #pragma unroll
  for (int nf = 0; nf < 5; ++nf)
    #pragma unroll
    for (int rr = 0; rr < 4; ++rr)
      red[wv][g*4 + rr][nf*16 + r] = acc2[nf][rr];
  __syncthreads();

  for (int e = tid; e < 16*D_; e += 512) {
    int row = e / D_, col = e % D_;
    float s = red[0][row][col];
    #pragma unroll
    for (int w = 1; w < 8; ++w) s += red[w][row][col];
    red[0][row][col] = s * (1.f/128.f) + b2[col] + vsh[row][col];  // /(16*8)
  }
  __syncthreads();
  if (tid < 256) {
    int row = tid >> 4, j = tid & 15;
    float v[5], s = 0.f, ss = 0.f;
    #pragma unroll
    for (int c = 0; c < 5; ++c) {
      v[c] = red[0][row][j + c*16];
      s += v[c]; ss += v[c]*v[c];
    }
    s  += __shfl_xor(s, 1, 16);  ss += __shfl_xor(ss, 1, 16);
    s  += __shfl_xor(s, 2, 16);  ss += __shfl_xor(ss, 2, 16);
    s  += __shfl_xor(s, 4, 16);  ss += __shfl_xor(ss, 4, 16);
    s  += __shfl_xor(s, 8, 16);  ss += __shfl_xor(ss, 8, 16);
    float mean = s * (1.f/D_);
    float var  = ss * (1.f/D_) - mean*mean;
    float inv  = rsqrtf(var + EPS_);
    int grow = bm + row;
    float xs[5];
    float s2 = 0.f, ss2 = 0.f;
    #pragma unroll
    for (int c = 0; c < 5; ++c) {
      int col = j + c*16;
      xs[c] = (v[c] - mean) * inv * low[col] + lob[col];
      x[(size_t)grow*D_ + col] = xs[c];
      s2 += xs[c]; ss2 += xs[c]*xs[c];
    }
    if (mode == 0) {
      s2  += __shfl_xor(s2, 1, 16);  ss2 += __shfl_xor(ss2, 1, 16);
      s2  += __shfl_xor(s2, 2, 16);  ss2 += __shfl_xor(ss2, 2, 16);
      s2  += __shfl_xor(s2, 4, 16);  ss2 += __shfl_xor(ss2, 4, 16);
      s2  += __shfl_xor(s2, 8, 16);  ss2 += __shfl_xor(ss2, 8, 16);
      float m2 = s2 * (1.f/D_);
      float v2 = ss2 * (1.f/D_) - m2*m2;
      float i2 = rsqrtf(v2 + EPS_);
      #pragma unroll
      for (int c = 0; c < 5; ++c) {
        int col = j + c*16;
        hnsh[row][col] = f2bf((xs[c] - m2) * i2 * liw[col] + lib[col]);
      }
      hnsh[row][D_ + j] = 0;
    } else {
      #pragma unroll
      for (int c = 0; c < 5; ++c)
        xnbf[(size_t)grow*KP_ + j + c*16] = f2bf(xs[c]);
      xnbf[(size_t)grow*KP_ + D_ + j] = 0;
    }
  }

  // ---- fused next-layer QKV: [16x96] @ [96x240] (15 N-tiles over 8 waves) ----
  if (mode == 0) {
    __syncthreads();
    for (int t = wv; t < 15; t += 8) {
      f32x4 acc = {};
      #pragma unroll
      for (int ks = 0; ks < KP_; ks += 32) {
        bf16x8 a  = *(const bf16x8*)(&hnsh[r][ks + g*8]);
        bf16x8 bb = *(const bf16x8*)(wqkvT_n + (size_t)(t*16 + r)*KP_ + ks + g*8);
        acc = __builtin_amdgcn_mfma_f32_16x16x32_bf16(a, bb, acc, 0, 0, 0);
      }
      int col = t*16 + r;
      float bc = bqkv_n[col];
      #pragma unroll
      for (int rr = 0; rr < 4; ++rr) {
        int row = bm + g*4 + rr;
        float v = acc[rr] + bc;
        if (col < D_) q[(size_t)row*D_ + col] = v;
        else          kv[(size_t)row*2*D_ + (col - D_)] = v;
      }
    }
  }
}

// ============ final proj MFMA (+ lengths tail) ============
__global__ __launch_bounds__(256) void k_proj_mfma(const ushort_t* __restrict__ xbf,
    const ushort_t* __restrict__ pwT, const float* __restrict__ pb,
    const int* __restrict__ len, float* __restrict__ out) {
  int wv = threadIdx.x >> 6, lane = threadIdx.x & 63;
  int bm = blockIdx.x * 64;
  int bn = blockIdx.y * 128 + wv*32;
  int b  = blockIdx.z;
  int r = lane & 15, g = lane >> 4;
  f32x4 acc[4][2] = {};
  const ushort_t* Ab = xbf + ((size_t)(b*L_ + RCT_ + bm) + r)*KP_ + g*8;
  const ushort_t* Bb = pwT + (size_t)(bn + r)*KP_ + g*8;
  #pragma unroll
  for (int ks = 0; ks < KP_; ks += 32) {
    bf16x8 a[4], bfr[2];
    #pragma unroll
    for (int mf = 0; mf < 4; ++mf) a[mf]   = *(const bf16x8*)(Ab + mf*16*KP_ + ks);
    #pragma unroll
    for (int nf = 0; nf < 2; ++nf) bfr[nf] = *(const bf16x8*)(Bb + nf*16*KP_ + ks);
    #pragma unroll
    for (int mf = 0; mf < 4; ++mf)
      #pragma unroll
      for (int nf = 0; nf < 2; ++nf)
        acc[mf][nf] = __builtin_amdgcn_mfma_f32_16x16x32_bf16(a[mf], bfr[nf], acc[mf][nf], 0, 0, 0);
  }
  #pragma unroll
  for (int mf = 0; mf < 4; ++mf)
    #pragma unroll
    for (int nf = 0; nf < 2; ++nf) {
      int col = bn + nf*16 + r;
      float bc = pb[col];
      #pragma unroll
      for (int rr = 0; rr < 4; ++rr) {
        int row = bm + mf*16 + g*4 + rr;
        out[((size_t)b*TU_ + row)*OUTD_ + col] = acc[mf][nf][rr] + bc;
      }
    }
  if (blockIdx.x == 0 && blockIdx.y == 0 && blockIdx.z == 0 && threadIdx.x < B_)
    out[(size_t)B_*TU_*OUTD_ + threadIdx.x] = (float)len[threadIdx.x];
}

extern "C" void kernel_launch(void* const* d_in, const int* in_sizes, int n_in,
                              void* d_out, int out_size, void* d_ws, size_t ws_size,
                              hipStream_t stream) {
  const float* mel     = (const float*)d_in[0];
  const int*   lengths = (const int*)  d_in[1];
  const float* ln_in_w = (const float*)d_in[2];
  const float* ln_in_b = (const float*)d_in[3];
  const float* wq      = (const float*)d_in[4];
  const float* bq      = (const float*)d_in[5];
  const float* wkv     = (const float*)d_in[6];
  const float* bkv     = (const float*)d_in[7];
  const float* wo      = (const float*)d_in[8];
  const float* bo      = (const float*)d_in[9];
  const float* ln_ff_w = (const float*)d_in[10];
  const float* ln_ff_b = (const float*)d_in[11];
  const float* w1      = (const float*)d_in[12];
  const float* b1      = (const float*)d_in[13];
  const float* w2      = (const float*)d_in[14];
  const float* b2      = (const float*)d_in[15];
  const float* ln_o_w  = (const float*)d_in[16];
  const float* ln_o_b  = (const float*)d_in[17];
  const float* pw      = (const float*)d_in[18];
  const float* pb      = (const float*)d_in[19];
  float* out = (float*)d_out;

  float* ws = (float*)d_ws;
  float* x     = ws; ws += NR_*D_;
  float* qb    = ws; ws += NR_*D_;
  float* kvb   = ws; ws += NR_*2*D_;
  float* bqkv  = ws; ws += NLAYERS_*240;
  ushort_t* us = (ushort_t*)ws;
  ushort_t* xnbf  = us; us += NR_*KP_;
  ushort_t* attbf = us; us += NR_*KP_;
  ushort_t* wqkvT = us; us += S3_;
  ushort_t* woT   = us; us += S4_;
  ushort_t* pwT   = us; us += S5_;
  uchar_t* ub = (uchar_t*)us;
  uchar_t* w18 = ub; ub += S1_;
  uchar_t* w28 = ub; ub += S2_;

  k_wprep<<<(WPREP_N_ + 255)/256, 256, 0, stream>>>(w1, w2, wq, wkv, wo, pw, bq, bkv,
                                                    w18, w28, wqkvT, woT, pwT, bqkv);
  k_build_qkv<<<NR_/16, 512, 0, stream>>>(mel, ln_in_w, ln_in_b, wqkvT, bqkv, x, qb, kvb);

  for (int l = 0; l < NLAYERS_; ++l) {
    int last = (l == NLAYERS_-1);
    k_attn<<<dim3(NSEG_, B_, H_), 256, 0, stream>>>(qb, kvb, attbf);
    k_ffn_fused<<<NR_/16, 512, 0, stream>>>(attbf,
        woT + l*D_*KP_, bo + l*D_,
        w18 + (size_t)l*FFN_*KP_, b1 + l*FFN_,
        w28 + (size_t)l*D_*FFN_, b2 + l*D_,
        ln_ff_w + l*D_, ln_ff_b + l*D_,
        ln_o_w + l*D_, ln_o_b + l*D_,
        ln_in_w + (last ? 0 : (l+1)*D_), ln_in_b + (last ? 0 : (l+1)*D_),
        last, x, xnbf,
        wqkvT + (last ? 0 : (l+1)*256*KP_), bqkv + (last ? 0 : (l+1)*240),
        qb, kvb);
  }

  k_proj_mfma<<<dim3(TU_/64, OUTD_/128, B_), 256, 0, stream>>>(xnbf, pwT, pb, lengths, out);
}

// Round 10
// 157.255 us; speedup vs baseline: 1.9167x; 1.2509x over previous
//
#include <hip/hip_runtime.h>
#include <math.h>

#define B_    2
#define TU_   1024
#define D_    80
#define H_    8
#define DH_   10
#define FFN_  2048
#define SEG_  32
#define RC_   8
#define LC_   50
#define NSEG_ 32
#define RCT_  256
#define L_    1280
#define NLAYERS_ 4
#define OUTD_ 768
#define EPS_  1e-5f
#define SCALE_ 0.31622776601683794f
#define NR_   (B_*L_)                 // 2560
#define KP_   96                      // K pad 80->96

typedef __attribute__((ext_vector_type(8))) short bf16x8;
typedef __attribute__((ext_vector_type(4))) float f32x4;
typedef unsigned short ushort_t;

__device__ inline ushort_t f2bf(float f) {
  union { float f; unsigned u; } x; x.f = f;
  unsigned r = x.u + 0x7fffu + ((x.u >> 16) & 1u);   // RNE
  return (ushort_t)(r >> 16);
}
__device__ inline float bf2f(ushort_t u) {
  union { unsigned u; float f; } x; x.u = ((unsigned)u) << 16; return x.f;
}

// ============ one-shot weight prep (all bf16) ============
#define S1_ (NLAYERS_*FFN_*KP_)        // w1T [l][n2048][k96]
#define S2_ (NLAYERS_*D_*FFN_)         // w2T [l][n80][k2048]
#define S3_ (NLAYERS_*256*KP_)         // wqkvT [l][n256][k96] (scale folded in q cols)
#define S4_ (NLAYERS_*D_*KP_)          // woT [l][n80][k96]
#define S5_ (OUTD_*KP_)                // pwT [n768][k96]
#define S6_ (NLAYERS_*240)             // bqkv fp32 [l][240]
#define WPREP_N_ (S1_+S2_+S3_+S4_+S5_+S6_)

__global__ void k_wprep(const float* __restrict__ w1, const float* __restrict__ w2,
    const float* __restrict__ wq, const float* __restrict__ wkv,
    const float* __restrict__ wo, const float* __restrict__ pw,
    const float* __restrict__ bq, const float* __restrict__ bkv,
    ushort_t* __restrict__ w1T, ushort_t* __restrict__ w2T,
    ushort_t* __restrict__ wqkvT, ushort_t* __restrict__ woT,
    ushort_t* __restrict__ pwT, float* __restrict__ bqkv) {
  int idx = blockIdx.x * blockDim.x + threadIdx.x;
  if (idx < S1_) {
    int k = idx % KP_, n = (idx / KP_) % FFN_, l = idx / (KP_*FFN_);
    w1T[idx] = (k < D_) ? f2bf(w1[(l*D_ + k)*FFN_ + n]) : 0;
    return;
  }
  idx -= S1_;
  if (idx < S2_) {
    int k = idx % FFN_, n = (idx / FFN_) % D_, l = idx / (FFN_*D_);
    w2T[idx] = f2bf(w2[(l*FFN_ + k)*D_ + n]);
    return;
  }
  idx -= S2_;
  if (idx < S3_) {
    int k = idx % KP_, n = (idx / KP_) % 256, l = idx / (KP_*256);
    float v = 0.f;
    if (k < D_ && n < 240) {
      if (n < D_) v = wq[(l*D_ + k)*D_ + n] * SCALE_;
      else        v = wkv[(l*D_ + k)*2*D_ + (n - D_)];
    }
    wqkvT[idx] = f2bf(v);
    return;
  }
  idx -= S3_;
  if (idx < S4_) {
    int k = idx % KP_, n = (idx / KP_) % D_, l = idx / (KP_*D_);
    woT[idx] = (k < D_) ? f2bf(wo[(l*D_ + k)*D_ + n]) : 0;
    return;
  }
  idx -= S4_;
  if (idx < S5_) {
    int k = idx % KP_, n = idx / KP_;
    pwT[idx] = (k < D_) ? f2bf(pw[k*OUTD_ + n]) : 0;
    return;
  }
  idx -= S5_;
  if (idx < S6_) {
    int c = idx % 240, l = idx / 240;
    bqkv[idx] = (c < D_) ? bq[l*D_ + c] * SCALE_ : bkv[l*2*D_ + (c - D_)];
  }
}

// ============ merged: gather mel -> x + layer-0 LN_in + QKV MFMA -> q/kv ============
// grid 160, 512 thr (8 waves), 16 rows/block.
__global__ __launch_bounds__(512) void k_build_qkv(const float* __restrict__ mel,
    const float* __restrict__ lw, const float* __restrict__ lb,
    const ushort_t* __restrict__ wqkvT, const float* __restrict__ bqkv,
    float* __restrict__ x, float* __restrict__ q, float* __restrict__ kv) {
  int tid = threadIdx.x;
  int wv = tid >> 6, lane = tid & 63;
  int r = lane & 15, g = lane >> 4;
  int bm = blockIdx.x * 16;
  __shared__ ushort_t hnsh[16][KP_];

  if (tid < 256) {
    int row = tid >> 4, j = tid & 15;
    int grow = bm + row;
    int b = grow / L_, i = grow % L_;
    int srow = (i < RCT_) ? ((i >> 3) + 1)*SEG_ + (i & 7) : i - RCT_;
    float v[5], s = 0.f, ss = 0.f;
    #pragma unroll
    for (int c = 0; c < 5; ++c) {
      int col = j + c*16;
      v[c] = mel[((size_t)b*(TU_+RC_) + srow)*D_ + col];
      x[(size_t)grow*D_ + col] = v[c];
      s += v[c]; ss += v[c]*v[c];
    }
    s  += __shfl_xor(s, 1, 16);  ss += __shfl_xor(ss, 1, 16);
    s  += __shfl_xor(s, 2, 16);  ss += __shfl_xor(ss, 2, 16);
    s  += __shfl_xor(s, 4, 16);  ss += __shfl_xor(ss, 4, 16);
    s  += __shfl_xor(s, 8, 16);  ss += __shfl_xor(ss, 8, 16);
    float mean = s * (1.f/D_);
    float var  = ss * (1.f/D_) - mean*mean;
    float inv  = rsqrtf(var + EPS_);
    #pragma unroll
    for (int c = 0; c < 5; ++c) {
      int col = j + c*16;
      hnsh[row][col] = f2bf((v[c] - mean) * inv * lw[col] + lb[col]);
    }
    hnsh[row][D_ + j] = 0;
  }
  __syncthreads();

  for (int t = wv; t < 15; t += 8) {
    f32x4 acc = {};
    #pragma unroll
    for (int ks = 0; ks < KP_; ks += 32) {
      bf16x8 a  = *(const bf16x8*)(&hnsh[r][ks + g*8]);
      bf16x8 bb = *(const bf16x8*)(wqkvT + (size_t)(t*16 + r)*KP_ + ks + g*8);
      acc = __builtin_amdgcn_mfma_f32_16x16x32_bf16(a, bb, acc, 0, 0, 0);
    }
    int col = t*16 + r;
    float bc = bqkv[col];
    #pragma unroll
    for (int rr = 0; rr < 4; ++rr) {
      int row = bm + g*4 + rr;
      float v = acc[rr] + bc;
      if (col < D_) q[(size_t)row*D_ + col] = v;
      else          kv[(size_t)row*2*D_ + (col - D_)] = v;
    }
  }
}

// ============ block-sparse attention -> attbf bf16 [2560][96] ============
__global__ __launch_bounds__(256) void k_attn(const float* __restrict__ q,
    const float* __restrict__ kv, ushort_t* __restrict__ att) {
  int seg = blockIdx.x, b = blockIdx.y, h = blockIdx.z;
  int tid = threadIdx.x;
  int seg_start = seg*SEG_ - LC_; if (seg_start < 0) seg_start = 0;
  int kc = RC_ + (seg+1)*SEG_ - seg_start;       // <= 90
  __shared__ float Ksh[90][DH_];
  __shared__ float Vsh[90][DH_];
  __shared__ float Qsh[40][DH_];
  __shared__ float Ssh[40][90];
  __shared__ float inv_sh[40];
  for (int idx = tid; idx < kc*DH_; idx += 256) {
    int kk = idx / DH_, d = idx % DH_;
    int krow = (kk < RC_) ? seg*RC_ + kk : RCT_ + seg_start + (kk - RC_);
    const float* base = kv + (b*L_ + krow)*2*D_ + h*DH_ + d;
    Ksh[kk][d] = base[0];
    Vsh[kk][d] = base[D_];
  }
  for (int idx = tid; idx < 40*DH_; idx += 256) {
    int qi = idx / DH_, d = idx % DH_;
    int qrow = (qi < RC_) ? seg*RC_ + qi : RCT_ + seg*SEG_ + (qi - RC_);
    Qsh[qi][d] = q[(b*L_ + qrow)*D_ + h*DH_ + d];
  }
  __syncthreads();
  for (int p = tid; p < 40*kc; p += 256) {
    int qi = p / kc, kk = p - qi*kc;
    float s = 0.f;
    #pragma unroll
    for (int d = 0; d < DH_; ++d) s += Qsh[qi][d] * Ksh[kk][d];
    Ssh[qi][kk] = s;
  }
  __syncthreads();
  if (tid < 160) {
    int row = tid >> 2, j = tid & 3;
    float pm = -INFINITY;
    for (int kk = j; kk < kc; kk += 4) pm = fmaxf(pm, Ssh[row][kk]);
    pm = fmaxf(pm, __shfl_xor(pm, 1, 4));
    pm = fmaxf(pm, __shfl_xor(pm, 2, 4));
    float ps = 0.f;
    for (int kk = j; kk < kc; kk += 4) {
      float e = expf(Ssh[row][kk] - pm);
      Ssh[row][kk] = e;
      ps += e;
    }
    ps += __shfl_xor(ps, 1, 4);
    ps += __shfl_xor(ps, 2, 4);
    if (j == 0) inv_sh[row] = 1.f / ps;
  }
  __syncthreads();
  for (int o = tid; o < 40*DH_; o += 256) {
    int qi = o / DH_, d = o - qi*DH_;
    float acc = 0.f;
    for (int kk = 0; kk < kc; ++kk) acc += Ssh[qi][kk] * Vsh[kk][d];
    int qrow = (qi < RC_) ? seg*RC_ + qi : RCT_ + seg*SEG_ + (qi - RC_);
    att[(b*L_ + qrow)*KP_ + h*DH_ + d] = f2bf(acc * inv_sh[qi]);
  }
  if (h == 0) {  // zero K-pad cols 80..95
    for (int idx = tid; idx < 40*16; idx += 256) {
      int qi = idx >> 4, c = D_ + (idx & 15);
      int qrow = (qi < RC_) ? seg*RC_ + qi : RCT_ + seg*SEG_ + (qi - RC_);
      att[(b*L_ + qrow)*KP_ + c] = 0;
    }
  }
}

// ============ fused per-layer tail (16 waves): WO + res + LN_ff + FFN1 + FFN2 +
//              reduce + res + LN_out -> x, LN_in(next) -> QKV(next) ============
// grid 160, 1024 thr (16 waves, 4/SIMD). wave wv owns ff1 cols [wv*128, (wv+1)*128).
__global__ __launch_bounds__(1024) void k_ffn_fused(const ushort_t* __restrict__ attbf,
    const ushort_t* __restrict__ woT, const float* __restrict__ bo,
    const ushort_t* __restrict__ w1T, const float* __restrict__ b1,
    const ushort_t* __restrict__ w2T, const float* __restrict__ b2,
    const float* __restrict__ lfw, const float* __restrict__ lfb,
    const float* __restrict__ low, const float* __restrict__ lob,
    const float* __restrict__ liw, const float* __restrict__ lib, int mode,
    float* __restrict__ x, ushort_t* __restrict__ xnbf,
    const ushort_t* __restrict__ wqkvT_n, const float* __restrict__ bqkv_n,
    float* __restrict__ q, float* __restrict__ kv) {
  int tid = threadIdx.x;
  int wv = tid >> 6, lane = tid & 63;
  int r = lane & 15, g = lane >> 4;
  int bm = blockIdx.x * 16;
  __shared__ ushort_t attsh[16][KP_];
  __shared__ ushort_t hnsh[16][KP_];
  __shared__ ushort_t ff1sh[16][16][136];    // per-wave [16 rows][128+8 cols]
  __shared__ ushort_t redb[16][16][D_];      // bf16 FFN2 partials (16 waves)
  __shared__ float    vsh[16][D_];           // WO out -> residual -> FFN2 sum

  if (tid < 192) {
    int row = tid / 12, c = (tid % 12) * 8;
    *(bf16x8*)&attsh[row][c] = *(const bf16x8*)(attbf + (size_t)(bm+row)*KP_ + c);
  }
  __syncthreads();

  // ---- WO: waves 0..4 each compute one 16-col fragment (K=96) ----
  if (wv < 5) {
    f32x4 acc = {};
    #pragma unroll
    for (int ks = 0; ks < KP_; ks += 32) {
      bf16x8 a  = *(const bf16x8*)(&attsh[r][ks + g*8]);
      bf16x8 bb = *(const bf16x8*)(woT + (size_t)(wv*16 + r)*KP_ + ks + g*8);
      acc = __builtin_amdgcn_mfma_f32_16x16x32_bf16(a, bb, acc, 0, 0, 0);
    }
    #pragma unroll
    for (int rr = 0; rr < 4; ++rr)
      vsh[g*4 + rr][wv*16 + r] = acc[rr];
  }
  __syncthreads();

  // ---- bias + residual + LN_ff -> hnsh (res kept in vsh) ----
  if (tid < 256) {
    int row = tid >> 4, j = tid & 15;
    int grow = bm + row;
    float v[5], s = 0.f, ss = 0.f;
    #pragma unroll
    for (int c = 0; c < 5; ++c) {
      int col = j + c*16;
      v[c] = vsh[row][col] + bo[col] + x[(size_t)grow*D_ + col];
      vsh[row][col] = v[c];
      s += v[c]; ss += v[c]*v[c];
    }
    s  += __shfl_xor(s, 1, 16);  ss += __shfl_xor(ss, 1, 16);
    s  += __shfl_xor(s, 2, 16);  ss += __shfl_xor(ss, 2, 16);
    s  += __shfl_xor(s, 4, 16);  ss += __shfl_xor(ss, 4, 16);
    s  += __shfl_xor(s, 8, 16);  ss += __shfl_xor(ss, 8, 16);
    float mean = s * (1.f/D_);
    float var  = ss * (1.f/D_) - mean*mean;
    float inv  = rsqrtf(var + EPS_);
    #pragma unroll
    for (int c = 0; c < 5; ++c) {
      int col = j + c*16;
      hnsh[row][col] = f2bf((v[c] - mean) * inv * lfw[col] + lfb[col]);
    }
    hnsh[row][D_ + j] = 0;
  }
  __syncthreads();

  // ---- FFN1: M=16 x N=128(per wave) x K=96 ----
  f32x4 acc1[8];
  #pragma unroll
  for (int ni = 0; ni < 8; ++ni) acc1[ni] = (f32x4){0.f,0.f,0.f,0.f};
  int nbase = wv*128;
  #pragma unroll
  for (int ks = 0; ks < KP_; ks += 32) {
    bf16x8 a = *(const bf16x8*)(&hnsh[r][ks + g*8]);
    #pragma unroll
    for (int ni = 0; ni < 8; ++ni) {
      bf16x8 bb = *(const bf16x8*)(w1T + (size_t)(nbase + ni*16 + r)*KP_ + ks + g*8);
      acc1[ni] = __builtin_amdgcn_mfma_f32_16x16x32_bf16(a, bb, acc1[ni], 0, 0, 0);
    }
  }
  #pragma unroll
  for (int ni = 0; ni < 8; ++ni) {
    int col = nbase + ni*16 + r;
    float bc = b1[col];
    #pragma unroll
    for (int rr = 0; rr < 4; ++rr)
      ff1sh[wv][g*4 + rr][ni*16 + r] = f2bf(fmaxf(acc1[ni][rr] + bc, 0.f));
  }
  // same-wave write->read of ff1sh[wv]: compiler-ordered, no block barrier needed

  // ---- FFN2: M=16 x N=80 x K=128 (this wave's chunk) ----
  f32x4 acc2[5] = {};
  #pragma unroll
  for (int ks = 0; ks < 128; ks += 32) {
    bf16x8 a = *(const bf16x8*)(&ff1sh[wv][r][ks + g*8]);
    #pragma unroll
    for (int nf = 0; nf < 5; ++nf) {
      bf16x8 bb = *(const bf16x8*)(w2T + (size_t)(nf*16 + r)*FFN_ + wv*128 + ks + g*8);
      acc2[nf] = __builtin_amdgcn_mfma_f32_16x16x32_bf16(a, bb, acc2[nf], 0, 0, 0);
    }
  }
  #pragma unroll
  for (int nf = 0; nf < 5; ++nf)
    #pragma unroll
    for (int rr = 0; rr < 4; ++rr)
      redb[wv][g*4 + rr][nf*16 + r] = f2bf(acc2[nf][rr]);
  __syncthreads();

  // ---- 16-way partial reduce + bias + residual -> vsh ----
  for (int e = tid; e < 16*D_; e += 1024) {
    int row = e / D_, col = e % D_;
    float s = 0.f;
    #pragma unroll
    for (int w = 0; w < 16; ++w) s += bf2f(redb[w][row][col]);
    vsh[row][col] = s + b2[col] + vsh[row][col];
  }
  __syncthreads();
  if (tid < 256) {
    int row = tid >> 4, j = tid & 15;
    float v[5], s = 0.f, ss = 0.f;
    #pragma unroll
    for (int c = 0; c < 5; ++c) {
      v[c] = vsh[row][j + c*16];
      s += v[c]; ss += v[c]*v[c];
    }
    s  += __shfl_xor(s, 1, 16);  ss += __shfl_xor(ss, 1, 16);
    s  += __shfl_xor(s, 2, 16);  ss += __shfl_xor(ss, 2, 16);
    s  += __shfl_xor(s, 4, 16);  ss += __shfl_xor(ss, 4, 16);
    s  += __shfl_xor(s, 8, 16);  ss += __shfl_xor(ss, 8, 16);
    float mean = s * (1.f/D_);
    float var  = ss * (1.f/D_) - mean*mean;
    float inv  = rsqrtf(var + EPS_);
    int grow = bm + row;
    float xs[5];
    float s2 = 0.f, ss2 = 0.f;
    #pragma unroll
    for (int c = 0; c < 5; ++c) {
      int col = j + c*16;
      xs[c] = (v[c] - mean) * inv * low[col] + lob[col];
      x[(size_t)grow*D_ + col] = xs[c];
      s2 += xs[c]; ss2 += xs[c]*xs[c];
    }
    if (mode == 0) {
      s2  += __shfl_xor(s2, 1, 16);  ss2 += __shfl_xor(ss2, 1, 16);
      s2  += __shfl_xor(s2, 2, 16);  ss2 += __shfl_xor(ss2, 2, 16);
      s2  += __shfl_xor(s2, 4, 16);  ss2 += __shfl_xor(ss2, 4, 16);
      s2  += __shfl_xor(s2, 8, 16);  ss2 += __shfl_xor(ss2, 8, 16);
      float m2 = s2 * (1.f/D_);
      float v2 = ss2 * (1.f/D_) - m2*m2;
      float i2 = rsqrtf(v2 + EPS_);
      #pragma unroll
      for (int c = 0; c < 5; ++c) {
        int col = j + c*16;
        hnsh[row][col] = f2bf((xs[c] - m2) * i2 * liw[col] + lib[col]);
      }
      hnsh[row][D_ + j] = 0;
    } else {
      #pragma unroll
      for (int c = 0; c < 5; ++c)
        xnbf[(size_t)grow*KP_ + j + c*16] = f2bf(xs[c]);
      xnbf[(size_t)grow*KP_ + D_ + j] = 0;
    }
  }

  // ---- fused next-layer QKV: [16x96] @ [96x240] (15 N-tiles over 16 waves) ----
  if (mode == 0) {
    __syncthreads();
    if (wv < 15) {
      int t = wv;
      f32x4 acc = {};
      #pragma unroll
      for (int ks = 0; ks < KP_; ks += 32) {
        bf16x8 a  = *(const bf16x8*)(&hnsh[r][ks + g*8]);
        bf16x8 bb = *(const bf16x8*)(wqkvT_n + (size_t)(t*16 + r)*KP_ + ks + g*8);
        acc = __builtin_amdgcn_mfma_f32_16x16x32_bf16(a, bb, acc, 0, 0, 0);
      }
      int col = t*16 + r;
      float bc = bqkv_n[col];
      #pragma unroll
      for (int rr = 0; rr < 4; ++rr) {
        int row = bm + g*4 + rr;
        float v = acc[rr] + bc;
        if (col < D_) q[(size_t)row*D_ + col] = v;
        else          kv[(size_t)row*2*D_ + (col - D_)] = v;
      }
    }
  }
}

// ============ final proj MFMA (+ lengths tail) ============
__global__ __launch_bounds__(256) void k_proj_mfma(const ushort_t* __restrict__ xbf,
    const ushort_t* __restrict__ pwT, const float* __restrict__ pb,
    const int* __restrict__ len, float* __restrict__ out) {
  int wv = threadIdx.x >> 6, lane = threadIdx.x & 63;
  int bm = blockIdx.x * 64;
  int bn = blockIdx.y * 128 + wv*32;
  int b  = blockIdx.z;
  int r = lane & 15, g = lane >> 4;
  f32x4 acc[4][2] = {};
  const ushort_t* Ab = xbf + ((size_t)(b*L_ + RCT_ + bm) + r)*KP_ + g*8;
  const ushort_t* Bb = pwT + (size_t)(bn + r)*KP_ + g*8;
  #pragma unroll
  for (int ks = 0; ks < KP_; ks += 32) {
    bf16x8 a[4], bfr[2];
    #pragma unroll
    for (int mf = 0; mf < 4; ++mf) a[mf]   = *(const bf16x8*)(Ab + mf*16*KP_ + ks);
    #pragma unroll
    for (int nf = 0; nf < 2; ++nf) bfr[nf] = *(const bf16x8*)(Bb + nf*16*KP_ + ks);
    #pragma unroll
    for (int mf = 0; mf < 4; ++mf)
      #pragma unroll
      for (int nf = 0; nf < 2; ++nf)
        acc[mf][nf] = __builtin_amdgcn_mfma_f32_16x16x32_bf16(a[mf], bfr[nf], acc[mf][nf], 0, 0, 0);
  }
  #pragma unroll
  for (int mf = 0; mf < 4; ++mf)
    #pragma unroll
    for (int nf = 0; nf < 2; ++nf) {
      int col = bn + nf*16 + r;
      float bc = pb[col];
      #pragma unroll
      for (int rr = 0; rr < 4; ++rr) {
        int row = bm + mf*16 + g*4 + rr;
        out[((size_t)b*TU_ + row)*OUTD_ + col] = acc[mf][nf][rr] + bc;
      }
    }
  if (blockIdx.x == 0 && blockIdx.y == 0 && blockIdx.z == 0 && threadIdx.x < B_)
    out[(size_t)B_*TU_*OUTD_ + threadIdx.x] = (float)len[threadIdx.x];
}

extern "C" void kernel_launch(void* const* d_in, const int* in_sizes, int n_in,
                              void* d_out, int out_size, void* d_ws, size_t ws_size,
                              hipStream_t stream) {
  const float* mel     = (const float*)d_in[0];
  const int*   lengths = (const int*)  d_in[1];
  const float* ln_in_w = (const float*)d_in[2];
  const float* ln_in_b = (const float*)d_in[3];
  const float* wq      = (const float*)d_in[4];
  const float* bq      = (const float*)d_in[5];
  const float* wkv     = (const float*)d_in[6];
  const float* bkv     = (const float*)d_in[7];
  const float* wo      = (const float*)d_in[8];
  const float* bo      = (const float*)d_in[9];
  const float* ln_ff_w = (const float*)d_in[10];
  const float* ln_ff_b = (const float*)d_in[11];
  const float* w1      = (const float*)d_in[12];
  const float* b1      = (const float*)d_in[13];
  const float* w2      = (const float*)d_in[14];
  const float* b2      = (const float*)d_in[15];
  const float* ln_o_w  = (const float*)d_in[16];
  const float* ln_o_b  = (const float*)d_in[17];
  const float* pw      = (const float*)d_in[18];
  const float* pb      = (const float*)d_in[19];
  float* out = (float*)d_out;

  float* ws = (float*)d_ws;
  float* x     = ws; ws += NR_*D_;
  float* qb    = ws; ws += NR_*D_;
  float* kvb   = ws; ws += NR_*2*D_;
  float* bqkv  = ws; ws += NLAYERS_*240;
  ushort_t* us = (ushort_t*)ws;
  ushort_t* xnbf  = us; us += NR_*KP_;
  ushort_t* attbf = us; us += NR_*KP_;
  ushort_t* w1T   = us; us += S1_;
  ushort_t* w2T   = us; us += S2_;
  ushort_t* wqkvT = us; us += S3_;
  ushort_t* woT   = us; us += S4_;
  ushort_t* pwT   = us; us += S5_;

  k_wprep<<<(WPREP_N_ + 255)/256, 256, 0, stream>>>(w1, w2, wq, wkv, wo, pw, bq, bkv,
                                                    w1T, w2T, wqkvT, woT, pwT, bqkv);
  k_build_qkv<<<NR_/16, 512, 0, stream>>>(mel, ln_in_w, ln_in_b, wqkvT, bqkv, x, qb, kvb);

  for (int l = 0; l < NLAYERS_; ++l) {
    int last = (l == NLAYERS_-1);
    k_attn<<<dim3(NSEG_, B_, H_), 256, 0, stream>>>(qb, kvb, attbf);
    k_ffn_fused<<<NR_/16, 1024, 0, stream>>>(attbf,
        woT + l*D_*KP_, bo + l*D_,
        w1T + l*FFN_*KP_, b1 + l*FFN_,
        w2T + l*D_*FFN_, b2 + l*D_,
        ln_ff_w + l*D_, ln_ff_b + l*D_,
        ln_o_w + l*D_, ln_o_b + l*D_,
        ln_in_w + (last ? 0 : (l+1)*D_), ln_in_b + (last ? 0 : (l+1)*D_),
        last, x, xnbf,
        wqkvT + (last ? 0 : (l+1)*256*KP_), bqkv + (last ? 0 : (l+1)*240),
        qb, kvb);
  }

  k_proj_mfma<<<dim3(TU_/64, OUTD_/128, B_), 256, 0, stream>>>(xnbf, pwT, pb, lengths, out);
}

// Round 11
// 146.321 us; speedup vs baseline: 2.0599x; 1.0747x over previous
//
#include <hip/hip_runtime.h>
#include <math.h>

#define B_    2
#define TU_   1024
#define D_    80
#define H_    8
#define DH_   10
#define FFN_  2048
#define SEG_  32
#define RC_   8
#define LC_   50
#define NSEG_ 32
#define RCT_  256
#define L_    1280
#define NLAYERS_ 4
#define OUTD_ 768
#define EPS_  1e-5f
#define SCALE_ 0.31622776601683794f
#define NR_   (B_*L_)                 // 2560
#define KP_   96                      // K pad 80->96

typedef __attribute__((ext_vector_type(8))) short bf16x8;
typedef __attribute__((ext_vector_type(4))) float f32x4;
typedef unsigned short ushort_t;
typedef unsigned char uchar_t;
typedef long i64_t;

__device__ inline ushort_t f2bf(float f) {
  union { float f; unsigned u; } x; x.f = f;
  unsigned r = x.u + 0x7fffu + ((x.u >> 16) & 1u);   // RNE
  return (ushort_t)(r >> 16);
}
__device__ inline float bf2f(ushort_t u) {
  union { unsigned u; float f; } x; x.u = ((unsigned)u) << 16; return x.f;
}
// HW fp8 e4m3 convert (gfx950: v_cvt_pk_fp8_f32, RNE, saturating)
__device__ inline uchar_t f2fp8(float f) {
  return (uchar_t)(__builtin_amdgcn_cvt_pk_fp8_f32(f, f, 0, false) & 0xff);
}

// ============ one-shot weight prep ============
#define S1_ (NLAYERS_*FFN_*KP_)        // w18 fp8 [l][n2048][k96], x16
#define S2_ (NLAYERS_*D_*FFN_)         // w28 fp8 [l][n80][k2048], x16
#define S3_ (NLAYERS_*256*KP_)         // wqkvT bf16 [l][n256][k96] (scale folded in q cols)
#define S4_ (NLAYERS_*D_*KP_)          // woT bf16 [l][n80][k96]
#define S5_ (OUTD_*KP_)                // pwT bf16 [n768][k96]
#define S6_ (NLAYERS_*240)             // bqkv fp32 [l][240]
#define WPREP_N_ (S1_+S2_+S3_+S4_+S5_+S6_)

__global__ void k_wprep(const float* __restrict__ w1, const float* __restrict__ w2,
    const float* __restrict__ wq, const float* __restrict__ wkv,
    const float* __restrict__ wo, const float* __restrict__ pw,
    const float* __restrict__ bq, const float* __restrict__ bkv,
    uchar_t* __restrict__ w18, uchar_t* __restrict__ w28,
    ushort_t* __restrict__ wqkvT, ushort_t* __restrict__ woT,
    ushort_t* __restrict__ pwT, float* __restrict__ bqkv) {
  int idx = blockIdx.x * blockDim.x + threadIdx.x;
  if (idx < S1_) {
    int k = idx % KP_, n = (idx / KP_) % FFN_, l = idx / (KP_*FFN_);
    w18[idx] = (k < D_) ? f2fp8(w1[(l*D_ + k)*FFN_ + n] * 16.f) : 0;
    return;
  }
  idx -= S1_;
  if (idx < S2_) {
    int k = idx % FFN_, n = (idx / FFN_) % D_, l = idx / (FFN_*D_);
    w28[idx] = f2fp8(w2[(l*FFN_ + k)*D_ + n] * 16.f);
    return;
  }
  idx -= S2_;
  if (idx < S3_) {
    int k = idx % KP_, n = (idx / KP_) % 256, l = idx / (KP_*256);
    float v = 0.f;
    if (k < D_ && n < 240) {
      if (n < D_) v = wq[(l*D_ + k)*D_ + n] * SCALE_;
      else        v = wkv[(l*D_ + k)*2*D_ + (n - D_)];
    }
    wqkvT[idx] = f2bf(v);
    return;
  }
  idx -= S3_;
  if (idx < S4_) {
    int k = idx % KP_, n = (idx / KP_) % D_, l = idx / (KP_*D_);
    woT[idx] = (k < D_) ? f2bf(wo[(l*D_ + k)*D_ + n]) : 0;
    return;
  }
  idx -= S4_;
  if (idx < S5_) {
    int k = idx % KP_, n = idx / KP_;
    pwT[idx] = (k < D_) ? f2bf(pw[k*OUTD_ + n]) : 0;
    return;
  }
  idx -= S5_;
  if (idx < S6_) {
    int c = idx % 240, l = idx / 240;
    bqkv[idx] = (c < D_) ? bq[l*D_ + c] * SCALE_ : bkv[l*2*D_ + (c - D_)];
  }
}

// ============ merged: gather mel -> x + layer-0 LN_in + QKV MFMA -> q/kv ============
__global__ __launch_bounds__(512) void k_build_qkv(const float* __restrict__ mel,
    const float* __restrict__ lw, const float* __restrict__ lb,
    const ushort_t* __restrict__ wqkvT, const float* __restrict__ bqkv,
    float* __restrict__ x, float* __restrict__ q, float* __restrict__ kv) {
  int tid = threadIdx.x;
  int wv = tid >> 6, lane = tid & 63;
  int r = lane & 15, g = lane >> 4;
  int bm = blockIdx.x * 16;
  __shared__ ushort_t hnsh[16][KP_];

  if (tid < 256) {
    int row = tid >> 4, j = tid & 15;
    int grow = bm + row;
    int b = grow / L_, i = grow % L_;
    int srow = (i < RCT_) ? ((i >> 3) + 1)*SEG_ + (i & 7) : i - RCT_;
    float v[5], s = 0.f, ss = 0.f;
    #pragma unroll
    for (int c = 0; c < 5; ++c) {
      int col = j + c*16;
      v[c] = mel[((size_t)b*(TU_+RC_) + srow)*D_ + col];
      x[(size_t)grow*D_ + col] = v[c];
      s += v[c]; ss += v[c]*v[c];
    }
    s  += __shfl_xor(s, 1, 16);  ss += __shfl_xor(ss, 1, 16);
    s  += __shfl_xor(s, 2, 16);  ss += __shfl_xor(ss, 2, 16);
    s  += __shfl_xor(s, 4, 16);  ss += __shfl_xor(ss, 4, 16);
    s  += __shfl_xor(s, 8, 16);  ss += __shfl_xor(ss, 8, 16);
    float mean = s * (1.f/D_);
    float var  = ss * (1.f/D_) - mean*mean;
    float inv  = rsqrtf(var + EPS_);
    #pragma unroll
    for (int c = 0; c < 5; ++c) {
      int col = j + c*16;
      hnsh[row][col] = f2bf((v[c] - mean) * inv * lw[col] + lb[col]);
    }
    hnsh[row][D_ + j] = 0;
  }
  __syncthreads();

  for (int t = wv; t < 15; t += 8) {
    f32x4 acc = {};
    #pragma unroll
    for (int ks = 0; ks < KP_; ks += 32) {
      bf16x8 a  = *(const bf16x8*)(&hnsh[r][ks + g*8]);
      bf16x8 bb = *(const bf16x8*)(wqkvT + (size_t)(t*16 + r)*KP_ + ks + g*8);
      acc = __builtin_amdgcn_mfma_f32_16x16x32_bf16(a, bb, acc, 0, 0, 0);
    }
    int col = t*16 + r;
    float bc = bqkv[col];
    #pragma unroll
    for (int rr = 0; rr < 4; ++rr) {
      int row = bm + g*4 + rr;
      float v = acc[rr] + bc;
      if (col < D_) q[(size_t)row*D_ + col] = v;
      else          kv[(size_t)row*2*D_ + (col - D_)] = v;
    }
  }
}

// ============ block-sparse attention -> attbf bf16 [2560][96] ============
__global__ __launch_bounds__(256) void k_attn(const float* __restrict__ q,
    const float* __restrict__ kv, ushort_t* __restrict__ att) {
  int seg = blockIdx.x, b = blockIdx.y, h = blockIdx.z;
  int tid = threadIdx.x;
  int seg_start = seg*SEG_ - LC_; if (seg_start < 0) seg_start = 0;
  int kc = RC_ + (seg+1)*SEG_ - seg_start;       // <= 90
  __shared__ float Ksh[90][DH_];
  __shared__ float Vsh[90][DH_];
  __shared__ float Qsh[40][DH_];
  __shared__ float Ssh[40][90];
  __shared__ float inv_sh[40];
  for (int idx = tid; idx < kc*DH_; idx += 256) {
    int kk = idx / DH_, d = idx % DH_;
    int krow = (kk < RC_) ? seg*RC_ + kk : RCT_ + seg_start + (kk - RC_);
    const float* base = kv + (b*L_ + krow)*2*D_ + h*DH_ + d;
    Ksh[kk][d] = base[0];
    Vsh[kk][d] = base[D_];
  }
  for (int idx = tid; idx < 40*DH_; idx += 256) {
    int qi = idx / DH_, d = idx % DH_;
    int qrow = (qi < RC_) ? seg*RC_ + qi : RCT_ + seg*SEG_ + (qi - RC_);
    Qsh[qi][d] = q[(b*L_ + qrow)*D_ + h*DH_ + d];
  }
  __syncthreads();
  for (int p = tid; p < 40*kc; p += 256) {
    int qi = p / kc, kk = p - qi*kc;
    float s = 0.f;
    #pragma unroll
    for (int d = 0; d < DH_; ++d) s += Qsh[qi][d] * Ksh[kk][d];
    Ssh[qi][kk] = s;
  }
  __syncthreads();
  if (tid < 160) {
    int row = tid >> 2, j = tid & 3;
    float pm = -INFINITY;
    for (int kk = j; kk < kc; kk += 4) pm = fmaxf(pm, Ssh[row][kk]);
    pm = fmaxf(pm, __shfl_xor(pm, 1, 4));
    pm = fmaxf(pm, __shfl_xor(pm, 2, 4));
    float ps = 0.f;
    for (int kk = j; kk < kc; kk += 4) {
      float e = expf(Ssh[row][kk] - pm);
      Ssh[row][kk] = e;
      ps += e;
    }
    ps += __shfl_xor(ps, 1, 4);
    ps += __shfl_xor(ps, 2, 4);
    if (j == 0) inv_sh[row] = 1.f / ps;
  }
  __syncthreads();
  for (int o = tid; o < 40*DH_; o += 256) {
    int qi = o / DH_, d = o - qi*DH_;
    float acc = 0.f;
    for (int kk = 0; kk < kc; ++kk) acc += Ssh[qi][kk] * Vsh[kk][d];
    int qrow = (qi < RC_) ? seg*RC_ + qi : RCT_ + seg*SEG_ + (qi - RC_);
    att[(b*L_ + qrow)*KP_ + h*DH_ + d] = f2bf(acc * inv_sh[qi]);
  }
  if (h == 0) {  // zero K-pad cols 80..95
    for (int idx = tid; idx < 40*16; idx += 256) {
      int qi = idx >> 4, c = D_ + (idx & 15);
      int qrow = (qi < RC_) ? seg*RC_ + qi : RCT_ + seg*SEG_ + (qi - RC_);
      att[(b*L_ + qrow)*KP_ + c] = 0;
    }
  }
}

// ============ fused per-layer tail (16 waves): WO(bf16) + res + LN_ff +
//              FFN1(fp8) + FFN2(fp8) + reduce + res + LN_out -> x,
//              LN_in(next) -> QKV(next, bf16) ============
// grid 160, 1024 thr (16 waves). wave wv owns ff1 cols [wv*128, (wv+1)*128).
__global__ __launch_bounds__(1024) void k_ffn_fused(const ushort_t* __restrict__ attbf,
    const ushort_t* __restrict__ woT, const float* __restrict__ bo,
    const uchar_t* __restrict__ w18, const float* __restrict__ b1,
    const uchar_t* __restrict__ w28, const float* __restrict__ b2,
    const float* __restrict__ lfw, const float* __restrict__ lfb,
    const float* __restrict__ low, const float* __restrict__ lob,
    const float* __restrict__ liw, const float* __restrict__ lib, int mode,
    float* __restrict__ x, ushort_t* __restrict__ xnbf,
    const ushort_t* __restrict__ wqkvT_n, const float* __restrict__ bqkv_n,
    float* __restrict__ q, float* __restrict__ kv) {
  int tid = threadIdx.x;
  int wv = tid >> 6, lane = tid & 63;
  int r = lane & 15, g = lane >> 4;
  int bm = blockIdx.x * 16;
  __shared__ ushort_t attsh[16][KP_];
  __shared__ ushort_t hnsh[16][KP_];         // LN_in(next) out, QKV A-operand
  __shared__ uchar_t  hn8[16][104];          // fp8 LN_ff out (FFN1 A)
  __shared__ uchar_t  ff18[16][16][136];     // fp8 relu(ff1)*8, per-wave slice
  __shared__ ushort_t redb[16][16][D_];      // bf16 FFN2 partials
  __shared__ float    vsh[16][D_];           // WO out -> residual -> FFN2 sum

  if (tid < 192) {
    int row = tid / 12, c = (tid % 12) * 8;
    *(bf16x8*)&attsh[row][c] = *(const bf16x8*)(attbf + (size_t)(bm+row)*KP_ + c);
  }
  __syncthreads();

  // ---- WO: waves 0..4 each compute one 16-col fragment (K=96, bf16) ----
  if (wv < 5) {
    f32x4 acc = {};
    #pragma unroll
    for (int ks = 0; ks < KP_; ks += 32) {
      bf16x8 a  = *(const bf16x8*)(&attsh[r][ks + g*8]);
      bf16x8 bb = *(const bf16x8*)(woT + (size_t)(wv*16 + r)*KP_ + ks + g*8);
      acc = __builtin_amdgcn_mfma_f32_16x16x32_bf16(a, bb, acc, 0, 0, 0);
    }
    #pragma unroll
    for (int rr = 0; rr < 4; ++rr)
      vsh[g*4 + rr][wv*16 + r] = acc[rr];
  }
  __syncthreads();

  // ---- bias + residual + LN_ff -> hn8 (res kept in vsh) ----
  if (tid < 256) {
    int row = tid >> 4, j = tid & 15;
    int grow = bm + row;
    float v[5], s = 0.f, ss = 0.f;
    #pragma unroll
    for (int c = 0; c < 5; ++c) {
      int col = j + c*16;
      v[c] = vsh[row][col] + bo[col] + x[(size_t)grow*D_ + col];
      vsh[row][col] = v[c];
      s += v[c]; ss += v[c]*v[c];
    }
    s  += __shfl_xor(s, 1, 16);  ss += __shfl_xor(ss, 1, 16);
    s  += __shfl_xor(s, 2, 16);  ss += __shfl_xor(ss, 2, 16);
    s  += __shfl_xor(s, 4, 16);  ss += __shfl_xor(ss, 4, 16);
    s  += __shfl_xor(s, 8, 16);  ss += __shfl_xor(ss, 8, 16);
    float mean = s * (1.f/D_);
    float var  = ss * (1.f/D_) - mean*mean;
    float inv  = rsqrtf(var + EPS_);
    #pragma unroll
    for (int c = 0; c < 5; ++c) {
      int col = j + c*16;
      hn8[row][col] = f2fp8((v[c] - mean) * inv * lfw[col] + lfb[col]);
    }
    hn8[row][D_ + j] = 0;
  }
  __syncthreads();

  // ---- FFN1 fp8: M=16 x N=128(per wave) x K=96; out = acc/16 + b1, relu, x8 -> fp8 ----
  f32x4 acc1[8];
  #pragma unroll
  for (int ni = 0; ni < 8; ++ni) acc1[ni] = (f32x4){0.f,0.f,0.f,0.f};
  int nbase = wv*128;
  #pragma unroll
  for (int ks = 0; ks < KP_; ks += 32) {
    i64_t a = *(const i64_t*)(&hn8[r][ks + g*8]);
    #pragma unroll
    for (int ni = 0; ni < 8; ++ni) {
      i64_t bb = *(const i64_t*)(w18 + (size_t)(nbase + ni*16 + r)*KP_ + ks + g*8);
      acc1[ni] = __builtin_amdgcn_mfma_f32_16x16x32_fp8_fp8(a, bb, acc1[ni], 0, 0, 0);
    }
  }
  #pragma unroll
  for (int ni = 0; ni < 8; ++ni) {
    int col = nbase + ni*16 + r;
    float bc = b1[col];
    #pragma unroll
    for (int rr = 0; rr < 4; ++rr) {
      float v = acc1[ni][rr] * 0.0625f + bc;          // /16 (weight scale)
      ff18[wv][g*4 + rr][ni*16 + r] = f2fp8(fmaxf(v, 0.f) * 8.f);
    }
  }
  // same-wave write->read of ff18[wv]: compiler-ordered, no block barrier needed

  // ---- FFN2 fp8: M=16 x N=80 x K=128 (this wave's chunk) ----
  f32x4 acc2[5] = {};
  #pragma unroll
  for (int ks = 0; ks < 128; ks += 32) {
    i64_t a = *(const i64_t*)(&ff18[wv][r][ks + g*8]);
    #pragma unroll
    for (int nf = 0; nf < 5; ++nf) {
      i64_t bb = *(const i64_t*)(w28 + (size_t)(nf*16 + r)*FFN_ + wv*128 + ks + g*8);
      acc2[nf] = __builtin_amdgcn_mfma_f32_16x16x32_fp8_fp8(a, bb, acc2[nf], 0, 0, 0);
    }
  }
  #pragma unroll
  for (int nf = 0; nf < 5; ++nf)
    #pragma unroll
    for (int rr = 0; rr < 4; ++rr)
      redb[wv][g*4 + rr][nf*16 + r] = f2bf(acc2[nf][rr]);
  __syncthreads();

  // ---- 16-way partial reduce /128 + bias + residual -> vsh ----
  for (int e = tid; e < 16*D_; e += 1024) {
    int row = e / D_, col = e % D_;
    float s = 0.f;
    #pragma unroll
    for (int w = 0; w < 16; ++w) s += bf2f(redb[w][row][col]);
    vsh[row][col] = s * (1.f/128.f) + b2[col] + vsh[row][col];
  }
  __syncthreads();
  if (tid < 256) {
    int row = tid >> 4, j = tid & 15;
    float v[5], s = 0.f, ss = 0.f;
    #pragma unroll
    for (int c = 0; c < 5; ++c) {
      v[c] = vsh[row][j + c*16];
      s += v[c]; ss += v[c]*v[c];
    }
    s  += __shfl_xor(s, 1, 16);  ss += __shfl_xor(ss, 1, 16);
    s  += __shfl_xor(s, 2, 16);  ss += __shfl_xor(ss, 2, 16);
    s  += __shfl_xor(s, 4, 16);  ss += __shfl_xor(ss, 4, 16);
    s  += __shfl_xor(s, 8, 16);  ss += __shfl_xor(ss, 8, 16);
    float mean = s * (1.f/D_);
    float var  = ss * (1.f/D_) - mean*mean;
    float inv  = rsqrtf(var + EPS_);
    int grow = bm + row;
    float xs[5];
    float s2 = 0.f, ss2 = 0.f;
    #pragma unroll
    for (int c = 0; c < 5; ++c) {
      int col = j + c*16;
      xs[c] = (v[c] - mean) * inv * low[col] + lob[col];
      x[(size_t)grow*D_ + col] = xs[c];
      s2 += xs[c]; ss2 += xs[c]*xs[c];
    }
    if (mode == 0) {
      s2  += __shfl_xor(s2, 1, 16);  ss2 += __shfl_xor(ss2, 1, 16);
      s2  += __shfl_xor(s2, 2, 16);  ss2 += __shfl_xor(ss2, 2, 16);
      s2  += __shfl_xor(s2, 4, 16);  ss2 += __shfl_xor(ss2, 4, 16);
      s2  += __shfl_xor(s2, 8, 16);  ss2 += __shfl_xor(ss2, 8, 16);
      float m2 = s2 * (1.f/D_);
      float v2 = ss2 * (1.f/D_) - m2*m2;
      float i2 = rsqrtf(v2 + EPS_);
      #pragma unroll
      for (int c = 0; c < 5; ++c) {
        int col = j + c*16;
        hnsh[row][col] = f2bf((xs[c] - m2) * i2 * liw[col] + lib[col]);
      }
      hnsh[row][D_ + j] = 0;
    } else {
      #pragma unroll
      for (int c = 0; c < 5; ++c)
        xnbf[(size_t)grow*KP_ + j + c*16] = f2bf(xs[c]);
      xnbf[(size_t)grow*KP_ + D_ + j] = 0;
    }
  }

  // ---- fused next-layer QKV: [16x96] @ [96x240] (15 N-tiles over 16 waves) ----
  if (mode == 0) {
    __syncthreads();
    if (wv < 15) {
      int t = wv;
      f32x4 acc = {};
      #pragma unroll
      for (int ks = 0; ks < KP_; ks += 32) {
        bf16x8 a  = *(const bf16x8*)(&hnsh[r][ks + g*8]);
        bf16x8 bb = *(const bf16x8*)(wqkvT_n + (size_t)(t*16 + r)*KP_ + ks + g*8);
        acc = __builtin_amdgcn_mfma_f32_16x16x32_bf16(a, bb, acc, 0, 0, 0);
      }
      int col = t*16 + r;
      float bc = bqkv_n[col];
      #pragma unroll
      for (int rr = 0; rr < 4; ++rr) {
        int row = bm + g*4 + rr;
        float v = acc[rr] + bc;
        if (col < D_) q[(size_t)row*D_ + col] = v;
        else          kv[(size_t)row*2*D_ + (col - D_)] = v;
      }
    }
  }
}

// ============ final proj MFMA (+ lengths tail) ============
__global__ __launch_bounds__(256) void k_proj_mfma(const ushort_t* __restrict__ xbf,
    const ushort_t* __restrict__ pwT, const float* __restrict__ pb,
    const int* __restrict__ len, float* __restrict__ out) {
  int wv = threadIdx.x >> 6, lane = threadIdx.x & 63;
  int bm = blockIdx.x * 64;
  int bn = blockIdx.y * 128 + wv*32;
  int b  = blockIdx.z;
  int r = lane & 15, g = lane >> 4;
  f32x4 acc[4][2] = {};
  const ushort_t* Ab = xbf + ((size_t)(b*L_ + RCT_ + bm) + r)*KP_ + g*8;
  const ushort_t* Bb = pwT + (size_t)(bn + r)*KP_ + g*8;
  #pragma unroll
  for (int ks = 0; ks < KP_; ks += 32) {
    bf16x8 a[4], bfr[2];
    #pragma unroll
    for (int mf = 0; mf < 4; ++mf) a[mf]   = *(const bf16x8*)(Ab + mf*16*KP_ + ks);
    #pragma unroll
    for (int nf = 0; nf < 2; ++nf) bfr[nf] = *(const bf16x8*)(Bb + nf*16*KP_ + ks);
    #pragma unroll
    for (int mf = 0; mf < 4; ++mf)
      #pragma unroll
      for (int nf = 0; nf < 2; ++nf)
        acc[mf][nf] = __builtin_amdgcn_mfma_f32_16x16x32_bf16(a[mf], bfr[nf], acc[mf][nf], 0, 0, 0);
  }
  #pragma unroll
  for (int mf = 0; mf < 4; ++mf)
    #pragma unroll
    for (int nf = 0; nf < 2; ++nf) {
      int col = bn + nf*16 + r;
      float bc = pb[col];
      #pragma unroll
      for (int rr = 0; rr < 4; ++rr) {
        int row = bm + mf*16 + g*4 + rr;
        out[((size_t)b*TU_ + row)*OUTD_ + col] = acc[mf][nf][rr] + bc;
      }
    }
  if (blockIdx.x == 0 && blockIdx.y == 0 && blockIdx.z == 0 && threadIdx.x < B_)
    out[(size_t)B_*TU_*OUTD_ + threadIdx.x] = (float)len[threadIdx.x];
}

extern "C" void kernel_launch(void* const* d_in, const int* in_sizes, int n_in,
                              void* d_out, int out_size, void* d_ws, size_t ws_size,
                              hipStream_t stream) {
  const float* mel     = (const float*)d_in[0];
  const int*   lengths = (const int*)  d_in[1];
  const float* ln_in_w = (const float*)d_in[2];
  const float* ln_in_b = (const float*)d_in[3];
  const float* wq      = (const float*)d_in[4];
  const float* bq      = (const float*)d_in[5];
  const float* wkv     = (const float*)d_in[6];
  const float* bkv     = (const float*)d_in[7];
  const float* wo      = (const float*)d_in[8];
  const float* bo      = (const float*)d_in[9];
  const float* ln_ff_w = (const float*)d_in[10];
  const float* ln_ff_b = (const float*)d_in[11];
  const float* w1      = (const float*)d_in[12];
  const float* b1      = (const float*)d_in[13];
  const float* w2      = (const float*)d_in[14];
  const float* b2      = (const float*)d_in[15];
  const float* ln_o_w  = (const float*)d_in[16];
  const float* ln_o_b  = (const float*)d_in[17];
  const float* pw      = (const float*)d_in[18];
  const float* pb      = (const float*)d_in[19];
  float* out = (float*)d_out;

  float* ws = (float*)d_ws;
  float* x     = ws; ws += NR_*D_;
  float* qb    = ws; ws += NR_*D_;
  float* kvb   = ws; ws += NR_*2*D_;
  float* bqkv  = ws; ws += NLAYERS_*240;
  ushort_t* us = (ushort_t*)ws;
  ushort_t* xnbf  = us; us += NR_*KP_;
  ushort_t* attbf = us; us += NR_*KP_;
  ushort_t* wqkvT = us; us += S3_;
  ushort_t* woT   = us; us += S4_;
  ushort_t* pwT   = us; us += S5_;
  uchar_t* ub = (uchar_t*)us;
  uchar_t* w18 = ub; ub += S1_;
  uchar_t* w28 = ub; ub += S2_;

  k_wprep<<<(WPREP_N_ + 255)/256, 256, 0, stream>>>(w1, w2, wq, wkv, wo, pw, bq, bkv,
                                                    w18, w28, wqkvT, woT, pwT, bqkv);
  k_build_qkv<<<NR_/16, 512, 0, stream>>>(mel, ln_in_w, ln_in_b, wqkvT, bqkv, x, qb, kvb);

  for (int l = 0; l < NLAYERS_; ++l) {
    int last = (l == NLAYERS_-1);
    k_attn<<<dim3(NSEG_, B_, H_), 256, 0, stream>>>(qb, kvb, attbf);
    k_ffn_fused<<<NR_/16, 1024, 0, stream>>>(attbf,
        woT + l*D_*KP_, bo + l*D_,
        w18 + (size_t)l*FFN_*KP_, b1 + l*FFN_,
        w28 + (size_t)l*D_*FFN_, b2 + l*D_,
        ln_ff_w + l*D_, ln_ff_b + l*D_,
        ln_o_w + l*D_, ln_o_b + l*D_,
        ln_in_w + (last ? 0 : (l+1)*D_), ln_in_b + (last ? 0 : (l+1)*D_),
        last, x, xnbf,
        wqkvT + (last ? 0 : (l+1)*256*KP_), bqkv + (last ? 0 : (l+1)*240),
        qb, kvb);
  }

  k_proj_mfma<<<dim3(TU_/64, OUTD_/128, B_), 256, 0, stream>>>(xnbf, pwT, pb, lengths, out);
}